// Round 4
// baseline (1707.980 us; speedup 1.0000x reference)
//
#include <hip/hip_runtime.h>
#include <hip/hip_bf16.h>

#define N_NODES 100000
#define R_REL   8
#define E_EDGES 800000
#define D_FEAT  128
#define B_BASES 4
#define RN      (R_REL * N_NODES)
#define RE      (R_REL * E_EDGES)          // 6.4M edges

// radix partition: 784 coarse buckets of 128 dst nodes each (p1 unchanged)
#define NBKT    784
#define BKT_CAP 9216                       // mean 8163, +11 sigma slack
#define P1_TPB  256
#define P1_EPT  32
#define P1_CHUNK (P1_TPB * P1_EPT)         // 8192 edges / WG
#define P1_NWG  ((RE + P1_CHUNK - 1) / P1_CHUNK)   // 782

// agg: 4 sub-buckets of 32 dst nodes per coarse bucket
#define SUB_PER_BKT 4
#define SGRID   (NBKT * SUB_PER_BKT)       // 3136
#define SUBCAP  2816                       // mean 2041, +17 sigma slack

typedef __attribute__((ext_vector_type(8))) short short8;
typedef __attribute__((ext_vector_type(4))) float floatx4;

__global__ __launch_bounds__(1024) void init_cursor_kernel(int* __restrict__ gcursor) {
    int t = threadIdx.x;
    if (t < NBKT) gcursor[t] = t * BKT_CAP;
}

// x (fp32) -> xb (bf162 pairs)
__global__ __launch_bounds__(256) void xcvt_kernel(
    const float* __restrict__ x, uint* __restrict__ xb) {
    int i = blockIdx.x * 256 + threadIdx.x;          // over N*64 pairs
    if (i >= N_NODES * 64) return;
    float2 v = *(const float2*)(x + 2 * (size_t)i);
    __hip_bfloat162 h = __float22bfloat162_rn(v);
    xb[i] = *(uint*)&h;
}

// wT[n][k] = bf16( k<512 ? bases[k][n] : loop_weight[k-512][n] )
__global__ __launch_bounds__(256) void wcvt_kernel(
    const float* __restrict__ bases, const float* __restrict__ loopw,
    unsigned short* __restrict__ wT) {
    int idx = blockIdx.x * 256 + threadIdx.x;        // over 128*640
    if (idx >= 128 * 640) return;
    int n = idx / 640, k = idx % 640;
    float v = (k < 512) ? bases[(size_t)k * 128 + n] : loopw[(size_t)(k - 512) * 128 + n];
    __hip_bfloat16 h = __float2bfloat16(v);
    wT[idx] = *(unsigned short*)&h;
}

// wT2[l][n][k] = bf16(ngnn_w[l][k][n])
__global__ __launch_bounds__(256) void wcvt2_kernel(
    const float* __restrict__ ngnn_w, unsigned short* __restrict__ wT2) {
    int idx = blockIdx.x * 256 + threadIdx.x;        // over 2*128*128
    if (idx >= 2 * 128 * 128) return;
    int l = idx >> 14, rem = idx & 16383;
    int n = rem >> 7, k = rem & 127;
    float v = ngnn_w[(size_t)l * 16384 + (size_t)k * 128 + n];
    __hip_bfloat16 h = __float2bfloat16(v);
    wT2[idx] = *(unsigned short*)&h;
}

// ---- pass 1: partition edges into coarse dst-buckets (coalesced writes) ---
// record = src(17b) | dst_low(7b)<<17 | r(3b)<<24
__global__ __launch_bounds__(256) void p1_kernel(
    const int* __restrict__ src, const int* __restrict__ dst,
    int* __restrict__ gcursor, int* __restrict__ ebuf2) {
    __shared__ int hist[NBKT];
    __shared__ int cnt2[NBKT];
    __shared__ int basebkt[NBKT];
    __shared__ int lofs[NBKT];
    __shared__ int aux[256];
    __shared__ int recs[P1_CHUNK];           // 32 KB
    __shared__ unsigned short bb[P1_CHUNK];  // 16 KB
    int t = threadIdx.x;
    for (int i = t; i < NBKT; i += 256) { hist[i] = 0; cnt2[i] = 0; }
    __syncthreads();

    int e0 = blockIdx.x * P1_CHUNK;
    int rec[P1_EPT];
    int bkt[P1_EPT];
#pragma unroll
    for (int i = 0; i < P1_EPT; ++i) {
        int e = e0 + i * P1_TPB + t;         // coalesced
        if (e < RE) {
            int d = dst[e];
            int s = src[e];
            int r = e / E_EDGES;             // magic-mul division
            bkt[i] = d >> 7;
            rec[i] = s | ((d & 127) << 17) | (r << 24);
            atomicAdd(&hist[bkt[i]], 1);     // native int ds_add
        } else bkt[i] = -1;
    }
    __syncthreads();

    // exclusive scan of hist[784]: 4 consecutive per thread + Hillis-Steele
    int k0 = t * 4;
    int c0 = (k0 + 0 < NBKT) ? hist[k0 + 0] : 0;
    int c1 = (k0 + 1 < NBKT) ? hist[k0 + 1] : 0;
    int c2 = (k0 + 2 < NBKT) ? hist[k0 + 2] : 0;
    int c3 = (k0 + 3 < NBKT) ? hist[k0 + 3] : 0;
    int s1 = c0 + c1, s2 = s1 + c2, s3 = s2 + c3;
    aux[t] = s3;
    __syncthreads();
    int vv = s3;
    for (int off = 1; off < 256; off <<= 1) {
        int yv = (t >= off) ? aux[t - off] : 0;
        __syncthreads();
        vv += yv;
        aux[t] = vv;
        __syncthreads();
    }
    int total = aux[255];
    int texcl = vv - s3;
    if (k0 + 0 < NBKT) lofs[k0 + 0] = texcl;
    if (k0 + 1 < NBKT) lofs[k0 + 1] = texcl + c0;
    if (k0 + 2 < NBKT) lofs[k0 + 2] = texcl + s1;
    if (k0 + 3 < NBKT) lofs[k0 + 3] = texcl + s2;
    __syncthreads();
    for (int i = t; i < NBKT; i += 256) {
        int hv = hist[i];
        basebkt[i] = (hv > 0) ? atomicAdd(&gcursor[i], hv) : 0;
    }
    __syncthreads();

    // reorder records into bucket-contiguous LDS slots
#pragma unroll
    for (int i = 0; i < P1_EPT; ++i) {
        if (bkt[i] >= 0) {
            int p = lofs[bkt[i]] + atomicAdd(&cnt2[bkt[i]], 1);
            recs[p] = rec[i];
            bb[p] = (unsigned short)bkt[i];
        }
    }
    __syncthreads();

    // writeout: consecutive i are mostly same-bucket runs
    for (int i = t; i < total; i += 256) {
        int b = bb[i];
        int p2 = basebkt[b] + (i - lofs[b]);
        if (p2 < (b + 1) * BKT_CAP) ebuf2[p2] = recs[i];
    }
}

// accumulate one uint4 (4 bf162 pairs = one edge's feature quad) -----------
#define ACC4(u) do { \
    ax0 += __uint_as_float((u).x << 16); ay0 += __uint_as_float((u).x & 0xFFFF0000u); \
    ax1 += __uint_as_float((u).y << 16); ay1 += __uint_as_float((u).y & 0xFFFF0000u); \
    ax2 += __uint_as_float((u).z << 16); ay2 += __uint_as_float((u).z & 0xFFFF0000u); \
    ax3 += __uint_as_float((u).w << 16); ay3 += __uint_as_float((u).w & 0xFFFF0000u); \
} while (0)

// ---- fused sort+gather v4: uint4 gather with LANE-LINEAR output ----------
// 512 thr (8 waves), 4 WGs/CU (~25 KB LDS). id = sub*784 + bucket keeps the
// 4 sub-WGs of one bucket on one XCD (784 % 8 == 0). Gather: eg = lane&3
// (edge slot), q = lane>>2 (feature quad): lane loads uint4 = pairs
// 4q..4q+3 of edge eg -> 4 edges per load instruction. After shfl_xor(1,2)
// reduce over the eg-group, lane l holds the sums for pairs 4(l>>2)..+3 and
// selects element l&3 == pair l -> store yrow[b*64+lane] is LANE-LINEAR
// (full-line coalesced; R2/R3's permuted store caused 16x write amp + RMW).
template <bool XB>
__global__ __launch_bounds__(512, 8) void agg3_kernel(
    const float* __restrict__ x,
    const uint*  __restrict__ xb,          // [N][64] bf162 pairs
    const int*   __restrict__ gcursor,
    const int*   __restrict__ ebuf2,
    const float* __restrict__ w_comp,
    __hip_bfloat162* __restrict__ y) {     // [N][256] bf162
    __shared__ int raw[SUBCAP];            // 11 KB
    __shared__ int sorted[SUBCAP];         // 11 KB (head doubles as scan aux)
    __shared__ int cursors[256];
    __shared__ int segbeg[256];
    __shared__ int nraw;
    const int t = threadIdx.x;
    const int bucket = blockIdx.x % NBKT;  // co-XCD mapping for the 4 sub-WGs
    const int sub    = blockIdx.x / NBKT;

    int cnt = gcursor[bucket] - bucket * BKT_CAP;
    if (cnt > BKT_CAP) cnt = BKT_CAP;
    const int* brec = ebuf2 + (size_t)bucket * BKT_CAP;
    if (t < 256) cursors[t] = 0;
    if (t == 0) nraw = 0;
    __syncthreads();

    const int lane = t & 63;
    const unsigned long long lmask = (1ull << lane) - 1ull;

    // single global pass: compact matching records into raw[] + histogram
    for (int i0 = 0; i0 < cnt; i0 += 512) {
        int i = i0 + t;
        int rec = (i < cnt) ? brec[i] : 0;
        bool match = (i < cnt) && ((((rec >> 17) & 127) >> 5) == sub);
        unsigned long long mask = __ballot(match);
        int base = 0;
        if (lane == 0) base = atomicAdd(&nraw, (int)__popcll(mask));
        base = __shfl(base, 0);
        if (match) {
            int p = base + (int)__popcll(mask & lmask);
            if (p < SUBCAP) {
                raw[p] = rec;
                int key = ((rec >> 17) & 31) * 8 + ((rec >> 24) & 7);
                atomicAdd(&cursors[key], 1);
            }
        }
    }
    __syncthreads();
    int n = nraw; if (n > SUBCAP) n = SUBCAP;

    // exclusive scan of 256 degrees (aux aliases sorted[0..511])
    int deg = (t < 256) ? cursors[t] : 0;
    int* aux = sorted;
    aux[t] = deg;
    __syncthreads();
    int vv = deg;
    for (int off = 1; off < 256; off <<= 1) {
        int yv = (t >= off && t < 256) ? aux[t - off] : 0;
        __syncthreads();
        vv += yv;
        aux[t] = vv;
        __syncthreads();
    }
    if (t < 256) {
        cursors[t] = vv - deg;
        segbeg[t]  = vv - deg;
    }
    __syncthreads();

    // in-LDS scatter to sorted order (src ids only)
    for (int i = t; i < n; i += 512) {
        int rec = raw[i];
        int key = ((rec >> 17) & 31) * 8 + ((rec >> 24) & 7);
        int pos = atomicAdd(&cursors[key], 1);   // ds_add_rtn_u32
        sorted[pos] = rec & 0x1FFFF;
    }
    __syncthreads();

    // gather: wave owns 4 nodes; per (node,r) segment sum then basis fold
    const int wid = t >> 6;
    if (XB) {
        const int eg = lane & 3;           // edge slot 0..3
        const int q  = lane >> 2;          // feature quad (pairs 4q..4q+3)
        const uint* xbq = xb + 4 * q;
        for (int nn = 0; nn < 4; ++nn) {
            int nl = wid * 4 + nn;                   // 0..31 within sub-bucket
            int node = bucket * 128 + sub * 32 + nl;
            int key0 = nl * 8;
            float2 a0[B_BASES], a1[B_BASES], a2[B_BASES], a3[B_BASES];
#pragma unroll
            for (int b = 0; b < B_BASES; ++b) {
                a0[b] = make_float2(0.f, 0.f); a1[b] = make_float2(0.f, 0.f);
                a2[b] = make_float2(0.f, 0.f); a3[b] = make_float2(0.f, 0.f);
            }
#pragma unroll
            for (int r = 0; r < R_REL; ++r) {
                int b0 = segbeg[key0 + r];
                int e0 = cursors[key0 + r];      // post-scatter == segment end
                int len = e0 - b0;
                float inv = 1.0f / (float)(len > 1 ? len : 1);
                float ax0 = 0.f, ay0 = 0.f, ax1 = 0.f, ay1 = 0.f;
                float ax2 = 0.f, ay2 = 0.f, ax3 = 0.f, ay3 = 0.f;
                int it = 0;
                for (; it + 8 <= len; it += 8) {     // 8 edges in flight
                    int sA = sorted[b0 + it + eg];
                    int sB = sorted[b0 + it + 4 + eg];
                    uint4 uA = *(const uint4*)(xbq + (size_t)sA * 64);
                    uint4 uB = *(const uint4*)(xbq + (size_t)sB * 64);
                    ACC4(uA); ACC4(uB);
                }
                if (it + 4 <= len) {
                    int sA = sorted[b0 + it + eg];
                    uint4 uA = *(const uint4*)(xbq + (size_t)sA * 64);
                    ACC4(uA);
                    it += 4;
                }
                int rem = len - it;
                if (rem > 0) {                       // masked tail (1..3 edges)
                    int idx = b0 + it + eg;
                    int s = sorted[idx < e0 ? idx : e0 - 1];
                    uint4 u = *(const uint4*)(xbq + (size_t)s * 64);
                    if (eg >= rem) { u.x = 0u; u.y = 0u; u.z = 0u; u.w = 0u; }
                    ACC4(u);
                }
#pragma unroll
                for (int b = 0; b < B_BASES; ++b) {
                    float c = w_comp[r * B_BASES + b] * inv;
                    a0[b].x = fmaf(c, ax0, a0[b].x); a0[b].y = fmaf(c, ay0, a0[b].y);
                    a1[b].x = fmaf(c, ax1, a1[b].x); a1[b].y = fmaf(c, ay1, a1[b].y);
                    a2[b].x = fmaf(c, ax2, a2[b].x); a2[b].y = fmaf(c, ay2, a2[b].y);
                    a3[b].x = fmaf(c, ax3, a3[b].x); a3[b].y = fmaf(c, ay3, a3[b].y);
                }
            }
            if (node < N_NODES) {
                uint* yrow = (uint*)(y + (size_t)node * 256);
#pragma unroll
                for (int b = 0; b < B_BASES; ++b) {
                    float v0x = a0[b].x, v0y = a0[b].y, v1x = a1[b].x, v1y = a1[b].y;
                    float v2x = a2[b].x, v2y = a2[b].y, v3x = a3[b].x, v3y = a3[b].y;
                    // reduce over the 4-lane eg-group (sums replicate in-group)
                    v0x += __shfl_xor(v0x, 1); v0x += __shfl_xor(v0x, 2);
                    v0y += __shfl_xor(v0y, 1); v0y += __shfl_xor(v0y, 2);
                    v1x += __shfl_xor(v1x, 1); v1x += __shfl_xor(v1x, 2);
                    v1y += __shfl_xor(v1y, 1); v1y += __shfl_xor(v1y, 2);
                    v2x += __shfl_xor(v2x, 1); v2x += __shfl_xor(v2x, 2);
                    v2y += __shfl_xor(v2y, 1); v2y += __shfl_xor(v2y, 2);
                    v3x += __shfl_xor(v3x, 1); v3x += __shfl_xor(v3x, 2);
                    v3y += __shfl_xor(v3y, 1); v3y += __shfl_xor(v3y, 2);
                    // lane l holds pairs 4(l>>2)..+3; element l&3 == pair l
                    float sx = (eg == 0) ? v0x : (eg == 1) ? v1x : (eg == 2) ? v2x : v3x;
                    float sy = (eg == 0) ? v0y : (eg == 1) ? v1y : (eg == 2) ? v2y : v3y;
                    __hip_bfloat162 h = __float22bfloat162_rn(make_float2(sx, sy));
                    yrow[b * 64 + lane] = *(uint*)&h;   // lane-linear, full-line
                }
            }
        }
    } else {
        const float* xp = x + 2 * lane;
        for (int nn = 0; nn < 4; ++nn) {
            int nl = wid * 4 + nn;
            int node = bucket * 128 + sub * 32 + nl;
            int key0 = nl * 8;
            float2 acc[B_BASES];
#pragma unroll
            for (int b = 0; b < B_BASES; ++b) acc[b] = make_float2(0.f, 0.f);
#pragma unroll
            for (int r = 0; r < R_REL; ++r) {
                int b0 = segbeg[key0 + r];
                int e0 = cursors[key0 + r];
                int d = e0 - b0;
                float inv = 1.0f / (float)(d > 1 ? d : 1);
                float ax = 0.f, ay = 0.f;
                int i = b0;
                for (; i + 3 < e0; i += 4) {
                    int s0 = sorted[i], s1 = sorted[i + 1], s2 = sorted[i + 2], s3 = sorted[i + 3];
                    float2 a = *(const float2*)(xp + (size_t)s0 * D_FEAT);
                    float2 b = *(const float2*)(xp + (size_t)s1 * D_FEAT);
                    float2 cc = *(const float2*)(xp + (size_t)s2 * D_FEAT);
                    float2 d2 = *(const float2*)(xp + (size_t)s3 * D_FEAT);
                    ax += (a.x + b.x) + (cc.x + d2.x);
                    ay += (a.y + b.y) + (cc.y + d2.y);
                }
                for (; i < e0; ++i) {
                    int s = sorted[i];
                    float2 a = *(const float2*)(xp + (size_t)s * D_FEAT);
                    ax += a.x; ay += a.y;
                }
#pragma unroll
                for (int b = 0; b < B_BASES; ++b) {
                    float coef = w_comp[r * B_BASES + b] * inv;
                    acc[b].x = fmaf(coef, ax, acc[b].x);
                    acc[b].y = fmaf(coef, ay, acc[b].y);
                }
            }
            if (node < N_NODES) {
                uint* yrow = (uint*)(y + (size_t)node * 256);
#pragma unroll
                for (int b = 0; b < B_BASES; ++b) {
                    __hip_bfloat162 h = __float22bfloat162_rn(acc[b]);
                    yrow[b * 64 + lane] = *(uint*)&h;
                }
            }
        }
    }
}

// ---- MFMA GEMM: hb1 = bf16(relu([y | bf16(x)] @ wT^T + bias)), K=640 ------
__global__ __launch_bounds__(256) void gemm_big_mfma(
    const short* __restrict__ y,           // [N][512] bf16
    const float* __restrict__ x,           // [N][128] fp32
    const unsigned short* __restrict__ wT, // [128][640] bf16
    const float* __restrict__ bias,
    unsigned short* __restrict__ hb1) {    // [N][128] bf16
    const int wave = threadIdx.x >> 6;
    const int lane = threadIdx.x & 63;
    const int quad = lane >> 4;
    const int l16  = lane & 15;
    const int row0 = blockIdx.x * 64 + wave * 16;
    int arow = row0 + l16;
    if (arow >= N_NODES) arow = N_NODES - 1;

    floatx4 acc[8];
#pragma unroll
    for (int nt = 0; nt < 8; ++nt) acc[nt] = (floatx4){0.f, 0.f, 0.f, 0.f};

    const short* yrow = y + (size_t)arow * 512;
    const float* xrow = x + (size_t)arow * 128;
    const int koff = quad * 8;

    for (int ks = 0; ks < 16; ++ks) {
        int k0 = ks * 32 + koff;
        short8 a = *(const short8*)(yrow + k0);
#pragma unroll
        for (int nt = 0; nt < 8; ++nt) {
            int n = nt * 16 + l16;
            short8 b = *(const short8*)((const short*)wT + (size_t)n * 640 + k0);
            acc[nt] = __builtin_amdgcn_mfma_f32_16x16x32_bf16(a, b, acc[nt], 0, 0, 0);
        }
    }
#pragma unroll
    for (int ks = 0; ks < 4; ++ks) {
        int k0 = ks * 32 + koff;
        float4 fa = *(const float4*)(xrow + k0);
        float4 fb = *(const float4*)(xrow + k0 + 4);
        union { short8 s; uint u[4]; } ua;
        __hip_bfloat162 h0 = __float22bfloat162_rn(make_float2(fa.x, fa.y));
        __hip_bfloat162 h1 = __float22bfloat162_rn(make_float2(fa.z, fa.w));
        __hip_bfloat162 h2 = __float22bfloat162_rn(make_float2(fb.x, fb.y));
        __hip_bfloat162 h3 = __float22bfloat162_rn(make_float2(fb.z, fb.w));
        ua.u[0] = *(uint*)&h0; ua.u[1] = *(uint*)&h1;
        ua.u[2] = *(uint*)&h2; ua.u[3] = *(uint*)&h3;
#pragma unroll
        for (int nt = 0; nt < 8; ++nt) {
            int n = nt * 16 + l16;
            short8 b = *(const short8*)((const short*)wT + (size_t)n * 640 + 512 + k0);
            acc[nt] = __builtin_amdgcn_mfma_f32_16x16x32_bf16(ua.s, b, acc[nt], 0, 0, 0);
        }
    }

#pragma unroll
    for (int nt = 0; nt < 8; ++nt) {
        int n = nt * 16 + l16;
        float bs = bias[n];
#pragma unroll
        for (int i = 0; i < 4; ++i) {
            int m = row0 + quad * 4 + i;
            if (m < N_NODES) {
                float v = fmaxf(acc[nt][i] + bs, 0.f);
                __hip_bfloat16 h = __float2bfloat16(v);
                hb1[(size_t)m * D_FEAT + n] = *(unsigned short*)&h;
            }
        }
    }
}

// ---- NGNN MFMA layer: C = relu(A @ wTl^T), A bf16 [N][128] ---------------
template <bool OUT_BF16>
__global__ __launch_bounds__(256) void ngnn_mfma(
    const short* __restrict__ A,             // [N][128] bf16
    const unsigned short* __restrict__ wTl,  // [128][128] bf16, n-major
    void* __restrict__ C) {
    const int wave = threadIdx.x >> 6;
    const int lane = threadIdx.x & 63;
    const int quad = lane >> 4;
    const int l16  = lane & 15;
    const int row0 = blockIdx.x * 64 + wave * 16;
    int arow = row0 + l16;
    if (arow >= N_NODES) arow = N_NODES - 1;

    floatx4 acc[8];
#pragma unroll
    for (int nt = 0; nt < 8; ++nt) acc[nt] = (floatx4){0.f, 0.f, 0.f, 0.f};

    const short* ar = A + (size_t)arow * 128;
    const int koff = quad * 8;
#pragma unroll
    for (int ks = 0; ks < 4; ++ks) {
        int k0 = ks * 32 + koff;
        short8 a = *(const short8*)(ar + k0);
#pragma unroll
        for (int nt = 0; nt < 8; ++nt) {
            int n = nt * 16 + l16;
            short8 b = *(const short8*)((const short*)wTl + (size_t)n * 128 + k0);
            acc[nt] = __builtin_amdgcn_mfma_f32_16x16x32_bf16(a, b, acc[nt], 0, 0, 0);
        }
    }

#pragma unroll
    for (int nt = 0; nt < 8; ++nt) {
        int n = nt * 16 + l16;
#pragma unroll
        for (int i = 0; i < 4; ++i) {
            int m = row0 + quad * 4 + i;
            if (m < N_NODES) {
                float v = fmaxf(acc[nt][i], 0.f);
                if (OUT_BF16) {
                    __hip_bfloat16 h = __float2bfloat16(v);
                    ((unsigned short*)C)[(size_t)m * D_FEAT + n] = *(unsigned short*)&h;
                } else {
                    ((float*)C)[(size_t)m * D_FEAT + n] = v;
                }
            }
        }
    }
}

extern "C" void kernel_launch(void* const* d_in, const int* in_sizes, int n_in,
                              void* d_out, int out_size, void* d_ws, size_t ws_size,
                              hipStream_t stream) {
    const float* x           = (const float*)d_in[0];
    const int*   edge_src    = (const int*)d_in[1];
    const int*   edge_dst    = (const int*)d_in[2];
    const float* w_comp      = (const float*)d_in[3];
    const float* bases       = (const float*)d_in[4];
    const float* loop_weight = (const float*)d_in[5];
    const float* h_bias      = (const float*)d_in[6];
    const float* ngnn_w      = (const float*)d_in[7];
    float* out = (float*)d_out;

    // workspace layout (~131.6 MB base; +25.6 MB optional xb)
    char* ws = (char*)d_ws;
    size_t off = 0;
    __hip_bfloat162* y = (__hip_bfloat162*)(ws + off);
    off += (size_t)N_NODES * 512 * 2;              // 102.4 MB
    int* ebuf2 = (int*)(ws + off);                 // 784*9216*4 = 28.9 MB
    unsigned short* hb1 = (unsigned short*)(ws + off);  // overlays ebuf2 (dead post-agg)
    off += (size_t)NBKT * BKT_CAP * 4;
    int* gcursor = (int*)(ws + off);
    off += 4096;
    unsigned short* wT = (unsigned short*)(ws + off);
    off += (size_t)128 * 640 * 2;                  // 160 KB
    unsigned short* wT2 = (unsigned short*)(ws + off);
    off += (size_t)2 * 128 * 128 * 2;              // 64 KB
    uint* xb = (uint*)(ws + off);
    size_t xb_bytes = (size_t)N_NODES * 64 * 4;    // 25.6 MB
    const bool use_bf16_x = (ws_size >= off + xb_bytes);   // ws_size constant across calls
    // hb2: overlays xb (dead post-agg) when present, else the y region (dead post-gemm_big)
    unsigned short* hb2 = use_bf16_x ? (unsigned short*)xb : (unsigned short*)y;

    const int GEMM_GRID = (N_NODES + 63) / 64;     // 1563

    // 0) weight/x conversions
    wcvt_kernel<<<(128 * 640 + 255) / 256, 256, 0, stream>>>(bases, loop_weight, wT);
    wcvt2_kernel<<<(2 * 128 * 128 + 255) / 256, 256, 0, stream>>>(ngnn_w, wT2);
    if (use_bf16_x)
        xcvt_kernel<<<(N_NODES * 64 + 255) / 256, 256, 0, stream>>>(x, xb);

    // 1) bucket partition
    init_cursor_kernel<<<1, 1024, 0, stream>>>(gcursor);
    p1_kernel<<<P1_NWG, P1_TPB, 0, stream>>>(edge_src, edge_dst, gcursor, ebuf2);

    // 2) fused filter + LDS-sort + gather -> y (bf16, basis-combined, deg-normalized)
    if (use_bf16_x)
        agg3_kernel<true><<<SGRID, 512, 0, stream>>>(x, xb, gcursor, ebuf2, w_comp, y);
    else
        agg3_kernel<false><<<SGRID, 512, 0, stream>>>(x, nullptr, gcursor, ebuf2, w_comp, y);

    // 3) hb1 = bf16(relu([y|x] @ [bases;loop_w] + bias))  -- MFMA
    gemm_big_mfma<<<GEMM_GRID, 256, 0, stream>>>(
        (const short*)y, x, wT, h_bias, hb1);

    // 4) NGNN: hb2 = bf16(relu(hb1 @ w0));  out = relu(hb2 @ w1)  -- MFMA
    ngnn_mfma<true><<<GEMM_GRID, 256, 0, stream>>>(
        (const short*)hb1, wT2, (void*)hb2);
    ngnn_mfma<false><<<GEMM_GRID, 256, 0, stream>>>(
        (const short*)hb2, wT2 + 128 * 128, (void*)out);
}

// Round 5
// 944.051 us; speedup vs baseline: 1.8092x; 1.8092x over previous
//
#include <hip/hip_runtime.h>
#include <hip/hip_bf16.h>

#define N_NODES 100000
#define R_REL   8
#define E_EDGES 800000
#define D_FEAT  128
#define B_BASES 4
#define RN      (R_REL * N_NODES)
#define RE      (R_REL * E_EDGES)          // 6.4M edges

// radix partition: 784 coarse buckets of 128 dst nodes each (p1 unchanged)
#define NBKT    784
#define BKT_CAP 9216                       // mean 8163, +11 sigma slack
#define P1_TPB  256
#define P1_EPT  32
#define P1_CHUNK (P1_TPB * P1_EPT)         // 8192 edges / WG
#define P1_NWG  ((RE + P1_CHUNK - 1) / P1_CHUNK)   // 782

// agg: 4 sub-buckets of 32 dst nodes per coarse bucket
#define SUB_PER_BKT 4
#define SGRID   (NBKT * SUB_PER_BKT)       // 3136
#define SUBCAP  2816                       // mean 2041, +17 sigma slack

typedef __attribute__((ext_vector_type(8))) short short8;
typedef __attribute__((ext_vector_type(4))) float floatx4;

__global__ __launch_bounds__(1024) void init_cursor_kernel(int* __restrict__ gcursor) {
    int t = threadIdx.x;
    if (t < NBKT) gcursor[t] = t * BKT_CAP;
}

// x (fp32) -> xb (bf162 pairs)
__global__ __launch_bounds__(256) void xcvt_kernel(
    const float* __restrict__ x, uint* __restrict__ xb) {
    int i = blockIdx.x * 256 + threadIdx.x;          // over N*64 pairs
    if (i >= N_NODES * 64) return;
    float2 v = *(const float2*)(x + 2 * (size_t)i);
    __hip_bfloat162 h = __float22bfloat162_rn(v);
    xb[i] = *(uint*)&h;
}

// wT[n][k] = bf16( k<512 ? bases[k][n] : loop_weight[k-512][n] )
__global__ __launch_bounds__(256) void wcvt_kernel(
    const float* __restrict__ bases, const float* __restrict__ loopw,
    unsigned short* __restrict__ wT) {
    int idx = blockIdx.x * 256 + threadIdx.x;        // over 128*640
    if (idx >= 128 * 640) return;
    int n = idx / 640, k = idx % 640;
    float v = (k < 512) ? bases[(size_t)k * 128 + n] : loopw[(size_t)(k - 512) * 128 + n];
    __hip_bfloat16 h = __float2bfloat16(v);
    wT[idx] = *(unsigned short*)&h;
}

// wT2[l][n][k] = bf16(ngnn_w[l][k][n])
__global__ __launch_bounds__(256) void wcvt2_kernel(
    const float* __restrict__ ngnn_w, unsigned short* __restrict__ wT2) {
    int idx = blockIdx.x * 256 + threadIdx.x;        // over 2*128*128
    if (idx >= 2 * 128 * 128) return;
    int l = idx >> 14, rem = idx & 16383;
    int n = rem >> 7, k = rem & 127;
    float v = ngnn_w[(size_t)l * 16384 + (size_t)k * 128 + n];
    __hip_bfloat16 h = __float2bfloat16(v);
    wT2[idx] = *(unsigned short*)&h;
}

// ---- pass 1: partition edges into coarse dst-buckets (coalesced writes) ---
// record = src(17b) | dst_low(7b)<<17 | r(3b)<<24
__global__ __launch_bounds__(256) void p1_kernel(
    const int* __restrict__ src, const int* __restrict__ dst,
    int* __restrict__ gcursor, int* __restrict__ ebuf2) {
    __shared__ int hist[NBKT];
    __shared__ int cnt2[NBKT];
    __shared__ int basebkt[NBKT];
    __shared__ int lofs[NBKT];
    __shared__ int aux[256];
    __shared__ int recs[P1_CHUNK];           // 32 KB
    __shared__ unsigned short bb[P1_CHUNK];  // 16 KB
    int t = threadIdx.x;
    for (int i = t; i < NBKT; i += 256) { hist[i] = 0; cnt2[i] = 0; }
    __syncthreads();

    int e0 = blockIdx.x * P1_CHUNK;
    int rec[P1_EPT];
    int bkt[P1_EPT];
#pragma unroll
    for (int i = 0; i < P1_EPT; ++i) {
        int e = e0 + i * P1_TPB + t;         // coalesced
        if (e < RE) {
            int d = dst[e];
            int s = src[e];
            int r = e / E_EDGES;             // magic-mul division
            bkt[i] = d >> 7;
            rec[i] = s | ((d & 127) << 17) | (r << 24);
            atomicAdd(&hist[bkt[i]], 1);     // native int ds_add
        } else bkt[i] = -1;
    }
    __syncthreads();

    // exclusive scan of hist[784]: 4 consecutive per thread + Hillis-Steele
    int k0 = t * 4;
    int c0 = (k0 + 0 < NBKT) ? hist[k0 + 0] : 0;
    int c1 = (k0 + 1 < NBKT) ? hist[k0 + 1] : 0;
    int c2 = (k0 + 2 < NBKT) ? hist[k0 + 2] : 0;
    int c3 = (k0 + 3 < NBKT) ? hist[k0 + 3] : 0;
    int s1 = c0 + c1, s2 = s1 + c2, s3 = s2 + c3;
    aux[t] = s3;
    __syncthreads();
    int vv = s3;
    for (int off = 1; off < 256; off <<= 1) {
        int yv = (t >= off) ? aux[t - off] : 0;
        __syncthreads();
        vv += yv;
        aux[t] = vv;
        __syncthreads();
    }
    int total = aux[255];
    int texcl = vv - s3;
    if (k0 + 0 < NBKT) lofs[k0 + 0] = texcl;
    if (k0 + 1 < NBKT) lofs[k0 + 1] = texcl + c0;
    if (k0 + 2 < NBKT) lofs[k0 + 2] = texcl + s1;
    if (k0 + 3 < NBKT) lofs[k0 + 3] = texcl + s2;
    __syncthreads();
    for (int i = t; i < NBKT; i += 256) {
        int hv = hist[i];
        basebkt[i] = (hv > 0) ? atomicAdd(&gcursor[i], hv) : 0;
    }
    __syncthreads();

    // reorder records into bucket-contiguous LDS slots
#pragma unroll
    for (int i = 0; i < P1_EPT; ++i) {
        if (bkt[i] >= 0) {
            int p = lofs[bkt[i]] + atomicAdd(&cnt2[bkt[i]], 1);
            recs[p] = rec[i];
            bb[p] = (unsigned short)bkt[i];
        }
    }
    __syncthreads();

    // writeout: consecutive i are mostly same-bucket runs
    for (int i = t; i < total; i += 256) {
        int b = bb[i];
        int p2 = basebkt[b] + (i - lofs[b]);
        if (p2 < (b + 1) * BKT_CAP) ebuf2[p2] = recs[i];
    }
}

// accumulate one uint4 (4 bf162 pairs = one edge's feature quad) -----------
#define ACC4(u) do { \
    ax0 += __uint_as_float((u).x << 16); ay0 += __uint_as_float((u).x & 0xFFFF0000u); \
    ax1 += __uint_as_float((u).y << 16); ay1 += __uint_as_float((u).y & 0xFFFF0000u); \
    ax2 += __uint_as_float((u).z << 16); ay2 += __uint_as_float((u).z & 0xFFFF0000u); \
    ax3 += __uint_as_float((u).w << 16); ay3 += __uint_as_float((u).w & 0xFFFF0000u); \
} while (0)

// ---- fused sort+gather v5: uint4 gather, LOW-REGISTER per-r reduce -------
// 512 thr (8 waves), ~25 KB LDS. id = sub*784 + bucket keeps the 4 sub-WGs
// of one bucket on one XCD (784 % 8 == 0). Gather: eg = lane&3 (edge slot),
// q = lane>>2 (feature quad): lane loads uint4 = pairs 4q..4q+3 of edge eg
// -> 4 edges per load instruction. The basis fold is done AFTER a per-r
// shfl_xor(1,2) reduce over the eg-group, so persistent state is just
// acc[4] float2 (8 regs) like the proven R1 kernel. R3/R4's 32-reg
// accumulator array + launch_bounds(512,8)'s 64-VGPR cap caused scratch
// spills (2 GB WRITE_SIZE); launch_bounds(512,6) adds headroom.
template <bool XB>
__global__ __launch_bounds__(512, 6) void agg3_kernel(
    const float* __restrict__ x,
    const uint*  __restrict__ xb,          // [N][64] bf162 pairs
    const int*   __restrict__ gcursor,
    const int*   __restrict__ ebuf2,
    const float* __restrict__ w_comp,
    __hip_bfloat162* __restrict__ y) {     // [N][256] bf162
    __shared__ int raw[SUBCAP];            // 11 KB
    __shared__ int sorted[SUBCAP];         // 11 KB (head doubles as scan aux)
    __shared__ int cursors[256];
    __shared__ int segbeg[256];
    __shared__ int nraw;
    const int t = threadIdx.x;
    const int bucket = blockIdx.x % NBKT;  // co-XCD mapping for the 4 sub-WGs
    const int sub    = blockIdx.x / NBKT;

    int cnt = gcursor[bucket] - bucket * BKT_CAP;
    if (cnt > BKT_CAP) cnt = BKT_CAP;
    const int* brec = ebuf2 + (size_t)bucket * BKT_CAP;
    if (t < 256) cursors[t] = 0;
    if (t == 0) nraw = 0;
    __syncthreads();

    const int lane = t & 63;
    const unsigned long long lmask = (1ull << lane) - 1ull;

    // single global pass: compact matching records into raw[] + histogram
    for (int i0 = 0; i0 < cnt; i0 += 512) {
        int i = i0 + t;
        int rec = (i < cnt) ? brec[i] : 0;
        bool match = (i < cnt) && ((((rec >> 17) & 127) >> 5) == sub);
        unsigned long long mask = __ballot(match);
        int base = 0;
        if (lane == 0) base = atomicAdd(&nraw, (int)__popcll(mask));
        base = __shfl(base, 0);
        if (match) {
            int p = base + (int)__popcll(mask & lmask);
            if (p < SUBCAP) {
                raw[p] = rec;
                int key = ((rec >> 17) & 31) * 8 + ((rec >> 24) & 7);
                atomicAdd(&cursors[key], 1);
            }
        }
    }
    __syncthreads();
    int n = nraw; if (n > SUBCAP) n = SUBCAP;

    // exclusive scan of 256 degrees (aux aliases sorted[0..511])
    int deg = (t < 256) ? cursors[t] : 0;
    int* aux = sorted;
    aux[t] = deg;
    __syncthreads();
    int vv = deg;
    for (int off = 1; off < 256; off <<= 1) {
        int yv = (t >= off && t < 256) ? aux[t - off] : 0;
        __syncthreads();
        vv += yv;
        aux[t] = vv;
        __syncthreads();
    }
    if (t < 256) {
        cursors[t] = vv - deg;
        segbeg[t]  = vv - deg;
    }
    __syncthreads();

    // in-LDS scatter to sorted order (src ids only)
    for (int i = t; i < n; i += 512) {
        int rec = raw[i];
        int key = ((rec >> 17) & 31) * 8 + ((rec >> 24) & 7);
        int pos = atomicAdd(&cursors[key], 1);   // ds_add_rtn_u32
        sorted[pos] = rec & 0x1FFFF;
    }
    __syncthreads();

    // gather: wave owns 4 nodes; per (node,r) segment sum then basis fold
    const int wid = t >> 6;
    if (XB) {
        const int eg = lane & 3;           // edge slot 0..3
        const int q  = lane >> 2;          // feature quad (pairs 4q..4q+3)
        const uint* xbq = xb + 4 * q;
        for (int nn = 0; nn < 4; ++nn) {
            int nl = wid * 4 + nn;                   // 0..31 within sub-bucket
            int node = bucket * 128 + sub * 32 + nl;
            int key0 = nl * 8;
            float2 acc[B_BASES];
#pragma unroll
            for (int b = 0; b < B_BASES; ++b) acc[b] = make_float2(0.f, 0.f);
#pragma unroll
            for (int r = 0; r < R_REL; ++r) {
                int b0 = segbeg[key0 + r];
                int e0 = cursors[key0 + r];      // post-scatter == segment end
                int len = e0 - b0;
                float inv = 1.0f / (float)(len > 1 ? len : 1);
                float ax0 = 0.f, ay0 = 0.f, ax1 = 0.f, ay1 = 0.f;
                float ax2 = 0.f, ay2 = 0.f, ax3 = 0.f, ay3 = 0.f;
                int it = 0;
                for (; it + 8 <= len; it += 8) {     // 8 edges in flight
                    int sA = sorted[b0 + it + eg];
                    int sB = sorted[b0 + it + 4 + eg];
                    uint4 uA = *(const uint4*)(xbq + (size_t)sA * 64);
                    uint4 uB = *(const uint4*)(xbq + (size_t)sB * 64);
                    ACC4(uA); ACC4(uB);
                }
                if (it + 4 <= len) {
                    int sA = sorted[b0 + it + eg];
                    uint4 uA = *(const uint4*)(xbq + (size_t)sA * 64);
                    ACC4(uA);
                    it += 4;
                }
                int rem = len - it;
                if (rem > 0) {                       // masked tail (1..3 edges)
                    int idx = b0 + it + eg;
                    int s = sorted[idx < e0 ? idx : e0 - 1];
                    uint4 u = *(const uint4*)(xbq + (size_t)s * 64);
                    if (eg >= rem) { u.x = 0u; u.y = 0u; u.z = 0u; u.w = 0u; }
                    ACC4(u);
                }
                // per-r reduce over the 4-lane eg-group (DPP-cheap shfls);
                // afterwards every lane in the group holds the full sums
                // for pairs 4q..4q+3.
                ax0 += __shfl_xor(ax0, 1); ax0 += __shfl_xor(ax0, 2);
                ay0 += __shfl_xor(ay0, 1); ay0 += __shfl_xor(ay0, 2);
                ax1 += __shfl_xor(ax1, 1); ax1 += __shfl_xor(ax1, 2);
                ay1 += __shfl_xor(ay1, 1); ay1 += __shfl_xor(ay1, 2);
                ax2 += __shfl_xor(ax2, 1); ax2 += __shfl_xor(ax2, 2);
                ay2 += __shfl_xor(ay2, 1); ay2 += __shfl_xor(ay2, 2);
                ax3 += __shfl_xor(ax3, 1); ax3 += __shfl_xor(ax3, 2);
                ay3 += __shfl_xor(ay3, 1); ay3 += __shfl_xor(ay3, 2);
                // lane l owns pair l = 4q + eg -> select element eg
                float sx = (eg == 0) ? ax0 : (eg == 1) ? ax1 : (eg == 2) ? ax2 : ax3;
                float sy = (eg == 0) ? ay0 : (eg == 1) ? ay1 : (eg == 2) ? ay2 : ay3;
#pragma unroll
                for (int b = 0; b < B_BASES; ++b) {
                    float c = w_comp[r * B_BASES + b] * inv;
                    acc[b].x = fmaf(c, sx, acc[b].x);
                    acc[b].y = fmaf(c, sy, acc[b].y);
                }
            }
            if (node < N_NODES) {
                uint* yrow = (uint*)(y + (size_t)node * 256);
#pragma unroll
                for (int b = 0; b < B_BASES; ++b) {
                    __hip_bfloat162 h = __float22bfloat162_rn(acc[b]);
                    yrow[b * 64 + lane] = *(uint*)&h;   // lane-linear, full-line
                }
            }
        }
    } else {
        const float* xp = x + 2 * lane;
        for (int nn = 0; nn < 4; ++nn) {
            int nl = wid * 4 + nn;
            int node = bucket * 128 + sub * 32 + nl;
            int key0 = nl * 8;
            float2 acc[B_BASES];
#pragma unroll
            for (int b = 0; b < B_BASES; ++b) acc[b] = make_float2(0.f, 0.f);
#pragma unroll
            for (int r = 0; r < R_REL; ++r) {
                int b0 = segbeg[key0 + r];
                int e0 = cursors[key0 + r];
                int d = e0 - b0;
                float inv = 1.0f / (float)(d > 1 ? d : 1);
                float ax = 0.f, ay = 0.f;
                int i = b0;
                for (; i + 3 < e0; i += 4) {
                    int s0 = sorted[i], s1 = sorted[i + 1], s2 = sorted[i + 2], s3 = sorted[i + 3];
                    float2 a = *(const float2*)(xp + (size_t)s0 * D_FEAT);
                    float2 b = *(const float2*)(xp + (size_t)s1 * D_FEAT);
                    float2 cc = *(const float2*)(xp + (size_t)s2 * D_FEAT);
                    float2 d2 = *(const float2*)(xp + (size_t)s3 * D_FEAT);
                    ax += (a.x + b.x) + (cc.x + d2.x);
                    ay += (a.y + b.y) + (cc.y + d2.y);
                }
                for (; i < e0; ++i) {
                    int s = sorted[i];
                    float2 a = *(const float2*)(xp + (size_t)s * D_FEAT);
                    ax += a.x; ay += a.y;
                }
#pragma unroll
                for (int b = 0; b < B_BASES; ++b) {
                    float coef = w_comp[r * B_BASES + b] * inv;
                    acc[b].x = fmaf(coef, ax, acc[b].x);
                    acc[b].y = fmaf(coef, ay, acc[b].y);
                }
            }
            if (node < N_NODES) {
                uint* yrow = (uint*)(y + (size_t)node * 256);
#pragma unroll
                for (int b = 0; b < B_BASES; ++b) {
                    __hip_bfloat162 h = __float22bfloat162_rn(acc[b]);
                    yrow[b * 64 + lane] = *(uint*)&h;
                }
            }
        }
    }
}

// ---- MFMA GEMM: hb1 = bf16(relu([y | bf16(x)] @ wT^T + bias)), K=640 ------
__global__ __launch_bounds__(256) void gemm_big_mfma(
    const short* __restrict__ y,           // [N][512] bf16
    const float* __restrict__ x,           // [N][128] fp32
    const unsigned short* __restrict__ wT, // [128][640] bf16
    const float* __restrict__ bias,
    unsigned short* __restrict__ hb1) {    // [N][128] bf16
    const int wave = threadIdx.x >> 6;
    const int lane = threadIdx.x & 63;
    const int quad = lane >> 4;
    const int l16  = lane & 15;
    const int row0 = blockIdx.x * 64 + wave * 16;
    int arow = row0 + l16;
    if (arow >= N_NODES) arow = N_NODES - 1;

    floatx4 acc[8];
#pragma unroll
    for (int nt = 0; nt < 8; ++nt) acc[nt] = (floatx4){0.f, 0.f, 0.f, 0.f};

    const short* yrow = y + (size_t)arow * 512;
    const float* xrow = x + (size_t)arow * 128;
    const int koff = quad * 8;

    for (int ks = 0; ks < 16; ++ks) {
        int k0 = ks * 32 + koff;
        short8 a = *(const short8*)(yrow + k0);
#pragma unroll
        for (int nt = 0; nt < 8; ++nt) {
            int n = nt * 16 + l16;
            short8 b = *(const short8*)((const short*)wT + (size_t)n * 640 + k0);
            acc[nt] = __builtin_amdgcn_mfma_f32_16x16x32_bf16(a, b, acc[nt], 0, 0, 0);
        }
    }
#pragma unroll
    for (int ks = 0; ks < 4; ++ks) {
        int k0 = ks * 32 + koff;
        float4 fa = *(const float4*)(xrow + k0);
        float4 fb = *(const float4*)(xrow + k0 + 4);
        union { short8 s; uint u[4]; } ua;
        __hip_bfloat162 h0 = __float22bfloat162_rn(make_float2(fa.x, fa.y));
        __hip_bfloat162 h1 = __float22bfloat162_rn(make_float2(fa.z, fa.w));
        __hip_bfloat162 h2 = __float22bfloat162_rn(make_float2(fb.x, fb.y));
        __hip_bfloat162 h3 = __float22bfloat162_rn(make_float2(fb.z, fb.w));
        ua.u[0] = *(uint*)&h0; ua.u[1] = *(uint*)&h1;
        ua.u[2] = *(uint*)&h2; ua.u[3] = *(uint*)&h3;
#pragma unroll
        for (int nt = 0; nt < 8; ++nt) {
            int n = nt * 16 + l16;
            short8 b = *(const short8*)((const short*)wT + (size_t)n * 640 + 512 + k0);
            acc[nt] = __builtin_amdgcn_mfma_f32_16x16x32_bf16(ua.s, b, acc[nt], 0, 0, 0);
        }
    }

#pragma unroll
    for (int nt = 0; nt < 8; ++nt) {
        int n = nt * 16 + l16;
        float bs = bias[n];
#pragma unroll
        for (int i = 0; i < 4; ++i) {
            int m = row0 + quad * 4 + i;
            if (m < N_NODES) {
                float v = fmaxf(acc[nt][i] + bs, 0.f);
                __hip_bfloat16 h = __float2bfloat16(v);
                hb1[(size_t)m * D_FEAT + n] = *(unsigned short*)&h;
            }
        }
    }
}

// ---- NGNN MFMA layer: C = relu(A @ wTl^T), A bf16 [N][128] ---------------
template <bool OUT_BF16>
__global__ __launch_bounds__(256) void ngnn_mfma(
    const short* __restrict__ A,             // [N][128] bf16
    const unsigned short* __restrict__ wTl,  // [128][128] bf16, n-major
    void* __restrict__ C) {
    const int wave = threadIdx.x >> 6;
    const int lane = threadIdx.x & 63;
    const int quad = lane >> 4;
    const int l16  = lane & 15;
    const int row0 = blockIdx.x * 64 + wave * 16;
    int arow = row0 + l16;
    if (arow >= N_NODES) arow = N_NODES - 1;

    floatx4 acc[8];
#pragma unroll
    for (int nt = 0; nt < 8; ++nt) acc[nt] = (floatx4){0.f, 0.f, 0.f, 0.f};

    const short* ar = A + (size_t)arow * 128;
    const int koff = quad * 8;
#pragma unroll
    for (int ks = 0; ks < 4; ++ks) {
        int k0 = ks * 32 + koff;
        short8 a = *(const short8*)(ar + k0);
#pragma unroll
        for (int nt = 0; nt < 8; ++nt) {
            int n = nt * 16 + l16;
            short8 b = *(const short8*)((const short*)wTl + (size_t)n * 128 + k0);
            acc[nt] = __builtin_amdgcn_mfma_f32_16x16x32_bf16(a, b, acc[nt], 0, 0, 0);
        }
    }

#pragma unroll
    for (int nt = 0; nt < 8; ++nt) {
        int n = nt * 16 + l16;
#pragma unroll
        for (int i = 0; i < 4; ++i) {
            int m = row0 + quad * 4 + i;
            if (m < N_NODES) {
                float v = fmaxf(acc[nt][i], 0.f);
                if (OUT_BF16) {
                    __hip_bfloat16 h = __float2bfloat16(v);
                    ((unsigned short*)C)[(size_t)m * D_FEAT + n] = *(unsigned short*)&h;
                } else {
                    ((float*)C)[(size_t)m * D_FEAT + n] = v;
                }
            }
        }
    }
}

extern "C" void kernel_launch(void* const* d_in, const int* in_sizes, int n_in,
                              void* d_out, int out_size, void* d_ws, size_t ws_size,
                              hipStream_t stream) {
    const float* x           = (const float*)d_in[0];
    const int*   edge_src    = (const int*)d_in[1];
    const int*   edge_dst    = (const int*)d_in[2];
    const float* w_comp      = (const float*)d_in[3];
    const float* bases       = (const float*)d_in[4];
    const float* loop_weight = (const float*)d_in[5];
    const float* h_bias      = (const float*)d_in[6];
    const float* ngnn_w      = (const float*)d_in[7];
    float* out = (float*)d_out;

    // workspace layout (~131.6 MB base; +25.6 MB optional xb)
    char* ws = (char*)d_ws;
    size_t off = 0;
    __hip_bfloat162* y = (__hip_bfloat162*)(ws + off);
    off += (size_t)N_NODES * 512 * 2;              // 102.4 MB
    int* ebuf2 = (int*)(ws + off);                 // 784*9216*4 = 28.9 MB
    unsigned short* hb1 = (unsigned short*)(ws + off);  // overlays ebuf2 (dead post-agg)
    off += (size_t)NBKT * BKT_CAP * 4;
    int* gcursor = (int*)(ws + off);
    off += 4096;
    unsigned short* wT = (unsigned short*)(ws + off);
    off += (size_t)128 * 640 * 2;                  // 160 KB
    unsigned short* wT2 = (unsigned short*)(ws + off);
    off += (size_t)2 * 128 * 128 * 2;              // 64 KB
    uint* xb = (uint*)(ws + off);
    size_t xb_bytes = (size_t)N_NODES * 64 * 4;    // 25.6 MB
    const bool use_bf16_x = (ws_size >= off + xb_bytes);   // ws_size constant across calls
    // hb2: overlays xb (dead post-agg) when present, else the y region (dead post-gemm_big)
    unsigned short* hb2 = use_bf16_x ? (unsigned short*)xb : (unsigned short*)y;

    const int GEMM_GRID = (N_NODES + 63) / 64;     // 1563

    // 0) weight/x conversions
    wcvt_kernel<<<(128 * 640 + 255) / 256, 256, 0, stream>>>(bases, loop_weight, wT);
    wcvt2_kernel<<<(2 * 128 * 128 + 255) / 256, 256, 0, stream>>>(ngnn_w, wT2);
    if (use_bf16_x)
        xcvt_kernel<<<(N_NODES * 64 + 255) / 256, 256, 0, stream>>>(x, xb);

    // 1) bucket partition
    init_cursor_kernel<<<1, 1024, 0, stream>>>(gcursor);
    p1_kernel<<<P1_NWG, P1_TPB, 0, stream>>>(edge_src, edge_dst, gcursor, ebuf2);

    // 2) fused filter + LDS-sort + gather -> y (bf16, basis-combined, deg-normalized)
    if (use_bf16_x)
        agg3_kernel<true><<<SGRID, 512, 0, stream>>>(x, xb, gcursor, ebuf2, w_comp, y);
    else
        agg3_kernel<false><<<SGRID, 512, 0, stream>>>(x, nullptr, gcursor, ebuf2, w_comp, y);

    // 3) hb1 = bf16(relu([y|x] @ [bases;loop_w] + bias))  -- MFMA
    gemm_big_mfma<<<GEMM_GRID, 256, 0, stream>>>(
        (const short*)y, x, wT, h_bias, hb1);

    // 4) NGNN: hb2 = bf16(relu(hb1 @ w0));  out = relu(hb2 @ w1)  -- MFMA
    ngnn_mfma<true><<<GEMM_GRID, 256, 0, stream>>>(
        (const short*)hb1, wT2, (void*)hb2);
    ngnn_mfma<false><<<GEMM_GRID, 256, 0, stream>>>(
        (const short*)hb2, wT2 + 128 * 128, (void*)out);
}

// Round 6
// 675.361 us; speedup vs baseline: 2.5290x; 1.3978x over previous
//
#include <hip/hip_runtime.h>
#include <hip/hip_bf16.h>

#define N_NODES 100000
#define R_REL   8
#define E_EDGES 800000
#define D_FEAT  128
#define B_BASES 4
#define RN      (R_REL * N_NODES)
#define RE      (R_REL * E_EDGES)          // 6.4M edges

// radix partition: 784 coarse buckets of 128 dst nodes each
#define NBKT    784
#define BKT_CAP 9216                       // mean 8163, +11 sigma slack
#define P1_TPB  256
#define P1_EPT  32
#define P1_CHUNK (P1_TPB * P1_EPT)         // 8192 edges / WG
#define P1_NWG  ((RE + P1_CHUNK - 1) / P1_CHUNK)   // 782

// agg: 4 sub-buckets of 32 dst nodes per coarse bucket
#define SUB_PER_BKT 4
#define SGRID   (NBKT * SUB_PER_BKT)       // 3136
#define SUBCAP  2816                       // mean 2041, +17 sigma slack

typedef __attribute__((ext_vector_type(8))) short short8;
typedef __attribute__((ext_vector_type(4))) float floatx4;

__global__ __launch_bounds__(1024) void init_cursor_kernel(int* __restrict__ gcursor) {
    int t = threadIdx.x;
    if (t < NBKT) gcursor[t] = t * BKT_CAP;
}

// x (fp32) -> xb (bf162 pairs)
__global__ __launch_bounds__(256) void xcvt_kernel(
    const float* __restrict__ x, uint* __restrict__ xb) {
    int i = blockIdx.x * 256 + threadIdx.x;          // over N*64 pairs
    if (i >= N_NODES * 64) return;
    float2 v = *(const float2*)(x + 2 * (size_t)i);
    __hip_bfloat162 h = __float22bfloat162_rn(v);
    xb[i] = *(uint*)&h;
}

// wT[n][k] = bf16( k<512 ? bases[k][n] : loop_weight[k-512][n] )
__global__ __launch_bounds__(256) void wcvt_kernel(
    const float* __restrict__ bases, const float* __restrict__ loopw,
    unsigned short* __restrict__ wT) {
    int idx = blockIdx.x * 256 + threadIdx.x;        // over 128*640
    if (idx >= 128 * 640) return;
    int n = idx / 640, k = idx % 640;
    float v = (k < 512) ? bases[(size_t)k * 128 + n] : loopw[(size_t)(k - 512) * 128 + n];
    __hip_bfloat16 h = __float2bfloat16(v);
    wT[idx] = *(unsigned short*)&h;
}

// wT2[l][n][k] = bf16(ngnn_w[l][k][n])
__global__ __launch_bounds__(256) void wcvt2_kernel(
    const float* __restrict__ ngnn_w, unsigned short* __restrict__ wT2) {
    int idx = blockIdx.x * 256 + threadIdx.x;        // over 2*128*128
    if (idx >= 2 * 128 * 128) return;
    int l = idx >> 14, rem = idx & 16383;
    int n = rem >> 7, k = rem & 127;
    float v = ngnn_w[(size_t)l * 16384 + (size_t)k * 128 + n];
    __hip_bfloat16 h = __float2bfloat16(v);
    wT2[idx] = *(unsigned short*)&h;
}

// ---- pass 1: partition edges into coarse dst-buckets (coalesced writes) ---
// record = src(17b) | dst_low(7b)<<17 | r(3b)<<24
__global__ __launch_bounds__(256) void p1_kernel(
    const int* __restrict__ src, const int* __restrict__ dst,
    int* __restrict__ gcursor, int* __restrict__ ebuf2) {
    __shared__ int hist[NBKT];
    __shared__ int cnt2[NBKT];
    __shared__ int basebkt[NBKT];
    __shared__ int lofs[NBKT];
    __shared__ int aux[256];
    __shared__ int recs[P1_CHUNK];           // 32 KB
    __shared__ unsigned short bb[P1_CHUNK];  // 16 KB
    int t = threadIdx.x;
    for (int i = t; i < NBKT; i += 256) { hist[i] = 0; cnt2[i] = 0; }
    __syncthreads();

    int e0 = blockIdx.x * P1_CHUNK;
    int rec[P1_EPT];
    int bkt[P1_EPT];
#pragma unroll
    for (int i = 0; i < P1_EPT; ++i) {
        int e = e0 + i * P1_TPB + t;         // coalesced
        if (e < RE) {
            int d = dst[e];
            int s = src[e];
            int r = e / E_EDGES;             // magic-mul division
            bkt[i] = d >> 7;
            rec[i] = s | ((d & 127) << 17) | (r << 24);
            atomicAdd(&hist[bkt[i]], 1);     // native int ds_add
        } else bkt[i] = -1;
    }
    __syncthreads();

    // exclusive scan of hist[784]: 4 consecutive per thread + Hillis-Steele
    int k0 = t * 4;
    int c0 = (k0 + 0 < NBKT) ? hist[k0 + 0] : 0;
    int c1 = (k0 + 1 < NBKT) ? hist[k0 + 1] : 0;
    int c2 = (k0 + 2 < NBKT) ? hist[k0 + 2] : 0;
    int c3 = (k0 + 3 < NBKT) ? hist[k0 + 3] : 0;
    int s1 = c0 + c1, s2 = s1 + c2, s3 = s2 + c3;
    aux[t] = s3;
    __syncthreads();
    int vv = s3;
    for (int off = 1; off < 256; off <<= 1) {
        int yv = (t >= off) ? aux[t - off] : 0;
        __syncthreads();
        vv += yv;
        aux[t] = vv;
        __syncthreads();
    }
    int total = aux[255];
    int texcl = vv - s3;
    if (k0 + 0 < NBKT) lofs[k0 + 0] = texcl;
    if (k0 + 1 < NBKT) lofs[k0 + 1] = texcl + c0;
    if (k0 + 2 < NBKT) lofs[k0 + 2] = texcl + s1;
    if (k0 + 3 < NBKT) lofs[k0 + 3] = texcl + s2;
    __syncthreads();
    for (int i = t; i < NBKT; i += 256) {
        int hv = hist[i];
        basebkt[i] = (hv > 0) ? atomicAdd(&gcursor[i], hv) : 0;
    }
    __syncthreads();

    // reorder records into bucket-contiguous LDS slots
#pragma unroll
    for (int i = 0; i < P1_EPT; ++i) {
        if (bkt[i] >= 0) {
            int p = lofs[bkt[i]] + atomicAdd(&cnt2[bkt[i]], 1);
            recs[p] = rec[i];
            bb[p] = (unsigned short)bkt[i];
        }
    }
    __syncthreads();

    // writeout: consecutive i are mostly same-bucket runs
    for (int i = t; i < total; i += 256) {
        int b = bb[i];
        int p2 = basebkt[b] + (i - lofs[b]);
        if (p2 < (b + 1) * BKT_CAP) ebuf2[p2] = recs[i];
    }
}

// ---- fused sort+gather (exact R1 structure, proven 271 us) ---------------
// 512 thr (8 waves), 4 WGs/CU (~25 KB LDS). id = sub*784 + bucket: the 4
// sub-WGs of one bucket are congruent mod 8 (784 % 8 == 0) -> same XCD
// under round-robin dispatch, so the 4x coarse-bucket re-read hits one L2.
// Gather: per-lane 4B loads, full wave reads one edge row per unrolled slot
// (4 independent loads in flight per iteration). Store lane-linear.
template <bool XB>
__global__ __launch_bounds__(512, 8) void agg3_kernel(
    const float* __restrict__ x,
    const uint*  __restrict__ xb,          // [N][64] bf162 pairs
    const int*   __restrict__ gcursor,
    const int*   __restrict__ ebuf2,
    const float* __restrict__ w_comp,
    __hip_bfloat162* __restrict__ y) {     // [N][256] bf162
    __shared__ int raw[SUBCAP];            // 11 KB
    __shared__ int sorted[SUBCAP];         // 11 KB (head doubles as scan aux)
    __shared__ int cursors[256];
    __shared__ int segbeg[256];
    __shared__ int nraw;
    const int t = threadIdx.x;
    const int bucket = blockIdx.x % NBKT;  // co-XCD mapping for the 4 sub-WGs
    const int sub    = blockIdx.x / NBKT;

    int cnt = gcursor[bucket] - bucket * BKT_CAP;
    if (cnt > BKT_CAP) cnt = BKT_CAP;
    const int* brec = ebuf2 + (size_t)bucket * BKT_CAP;
    if (t < 256) cursors[t] = 0;
    if (t == 0) nraw = 0;
    __syncthreads();

    const int lane = t & 63;
    const unsigned long long lmask = (1ull << lane) - 1ull;

    // single global pass: compact matching records into raw[] + histogram
    for (int i0 = 0; i0 < cnt; i0 += 512) {
        int i = i0 + t;
        int rec = (i < cnt) ? brec[i] : 0;
        bool match = (i < cnt) && ((((rec >> 17) & 127) >> 5) == sub);
        unsigned long long mask = __ballot(match);
        int base = 0;
        if (lane == 0) base = atomicAdd(&nraw, (int)__popcll(mask));
        base = __shfl(base, 0);
        if (match) {
            int p = base + (int)__popcll(mask & lmask);
            if (p < SUBCAP) {
                raw[p] = rec;
                int key = ((rec >> 17) & 31) * 8 + ((rec >> 24) & 7);
                atomicAdd(&cursors[key], 1);
            }
        }
    }
    __syncthreads();
    int n = nraw; if (n > SUBCAP) n = SUBCAP;

    // exclusive scan of 256 degrees (aux aliases sorted[0..511])
    int deg = (t < 256) ? cursors[t] : 0;
    int* aux = sorted;
    aux[t] = deg;
    __syncthreads();
    int vv = deg;
    for (int off = 1; off < 256; off <<= 1) {
        int yv = (t >= off && t < 256) ? aux[t - off] : 0;
        __syncthreads();
        vv += yv;
        aux[t] = vv;
        __syncthreads();
    }
    if (t < 256) {
        cursors[t] = vv - deg;
        segbeg[t]  = vv - deg;
    }
    __syncthreads();

    // in-LDS scatter to sorted order (src ids only)
    for (int i = t; i < n; i += 512) {
        int rec = raw[i];
        int key = ((rec >> 17) & 31) * 8 + ((rec >> 24) & 7);
        int pos = atomicAdd(&cursors[key], 1);   // ds_add_rtn_u32
        sorted[pos] = rec & 0x1FFFF;
    }
    __syncthreads();

    // gather: wave owns 4 nodes; per (node,r) segment sum then basis fold
    const int wid = t >> 6;
    const float* xp  = x + 2 * lane;
    const uint*  xbp = xb + lane;
    for (int nn = 0; nn < 4; ++nn) {
        int nl = wid * 4 + nn;                   // 0..31 within sub-bucket
        int node = bucket * 128 + sub * 32 + nl;
        int key0 = nl * 8;
        float2 acc[B_BASES];
#pragma unroll
        for (int b = 0; b < B_BASES; ++b) acc[b] = make_float2(0.f, 0.f);
#pragma unroll
        for (int r = 0; r < R_REL; ++r) {
            int b0 = segbeg[key0 + r];
            int e0 = cursors[key0 + r];      // post-scatter == segment end
            int d = e0 - b0;
            float inv = 1.0f / (float)(d > 1 ? d : 1);
            float ax = 0.f, ay = 0.f;
            int i = b0;
            for (; i + 3 < e0; i += 4) {
                int s0 = sorted[i], s1 = sorted[i + 1], s2 = sorted[i + 2], s3 = sorted[i + 3];
                if (XB) {
                    uint u0 = xbp[(size_t)s0 * 64];
                    uint u1 = xbp[(size_t)s1 * 64];
                    uint u2 = xbp[(size_t)s2 * 64];
                    uint u3 = xbp[(size_t)s3 * 64];
                    ax += (__uint_as_float(u0 << 16) + __uint_as_float(u1 << 16))
                        + (__uint_as_float(u2 << 16) + __uint_as_float(u3 << 16));
                    ay += (__uint_as_float(u0 & 0xFFFF0000u) + __uint_as_float(u1 & 0xFFFF0000u))
                        + (__uint_as_float(u2 & 0xFFFF0000u) + __uint_as_float(u3 & 0xFFFF0000u));
                } else {
                    float2 a = *(const float2*)(xp + (size_t)s0 * D_FEAT);
                    float2 b = *(const float2*)(xp + (size_t)s1 * D_FEAT);
                    float2 cc = *(const float2*)(xp + (size_t)s2 * D_FEAT);
                    float2 d2 = *(const float2*)(xp + (size_t)s3 * D_FEAT);
                    ax += (a.x + b.x) + (cc.x + d2.x);
                    ay += (a.y + b.y) + (cc.y + d2.y);
                }
            }
            for (; i < e0; ++i) {
                int s = sorted[i];
                if (XB) {
                    uint u = xbp[(size_t)s * 64];
                    ax += __uint_as_float(u << 16);
                    ay += __uint_as_float(u & 0xFFFF0000u);
                } else {
                    float2 a = *(const float2*)(xp + (size_t)s * D_FEAT);
                    ax += a.x; ay += a.y;
                }
            }
#pragma unroll
            for (int b = 0; b < B_BASES; ++b) {
                float coef = w_comp[r * B_BASES + b] * inv;
                acc[b].x = fmaf(coef, ax, acc[b].x);
                acc[b].y = fmaf(coef, ay, acc[b].y);
            }
        }
        if (node < N_NODES) {
#pragma unroll
            for (int b = 0; b < B_BASES; ++b)
                y[(size_t)node * 256 + b * 64 + lane] = __float22bfloat162_rn(acc[b]);
        }
    }
}

// ---- fused MLP: out = relu(relu(relu([y|x]@wT^T + bias) @ w0) @ w1) ------
// Row-local chain: each wave owns 16 rows end-to-end; intermediate
// activations live in a per-wave padded LDS tile (16 x 136 bf16, row
// stride 272 B) that converts the MFMA C-fragment layout (row=quad*4+i,
// col=nt*16+l16) into the A-fragment layout (row=l16, k=ks*32+quad*8).
// Eliminates hb1/hb2 HBM round-trips (102 MB) and 2 launches.
#define TPAD 136
__global__ __launch_bounds__(256) void fused_mlp(
    const short* __restrict__ y,            // [N][512] bf16
    const float* __restrict__ x,            // [N][128] fp32
    const unsigned short* __restrict__ wT,  // [128][640] bf16, n-major
    const float* __restrict__ bias,
    const unsigned short* __restrict__ wT2, // [2][128][128] bf16, n-major
    float* __restrict__ out) {              // [N][128] fp32
    __shared__ short tile[4][16][TPAD];     // 17.4 KB
    const int wave = threadIdx.x >> 6;
    const int lane = threadIdx.x & 63;
    const int quad = lane >> 4;
    const int l16  = lane & 15;
    const int row0 = blockIdx.x * 64 + wave * 16;
    int arow = row0 + l16;
    if (arow >= N_NODES) arow = N_NODES - 1;
    short (*tl)[TPAD] = tile[wave];

    floatx4 acc[8];
#pragma unroll
    for (int nt = 0; nt < 8; ++nt) acc[nt] = (floatx4){0.f, 0.f, 0.f, 0.f};

    // ---- layer 0: [y | bf16(x)] @ wT^T, K=640 ----
    const short* yrow = y + (size_t)arow * 512;
    const float* xrow = x + (size_t)arow * 128;
    const int koff = quad * 8;

    for (int ks = 0; ks < 16; ++ks) {
        int k0 = ks * 32 + koff;
        short8 a = *(const short8*)(yrow + k0);
#pragma unroll
        for (int nt = 0; nt < 8; ++nt) {
            int n = nt * 16 + l16;
            short8 b = *(const short8*)((const short*)wT + (size_t)n * 640 + k0);
            acc[nt] = __builtin_amdgcn_mfma_f32_16x16x32_bf16(a, b, acc[nt], 0, 0, 0);
        }
    }
#pragma unroll
    for (int ks = 0; ks < 4; ++ks) {
        int k0 = ks * 32 + koff;
        float4 fa = *(const float4*)(xrow + k0);
        float4 fb = *(const float4*)(xrow + k0 + 4);
        union { short8 s; uint u[4]; } ua;
        __hip_bfloat162 h0 = __float22bfloat162_rn(make_float2(fa.x, fa.y));
        __hip_bfloat162 h1 = __float22bfloat162_rn(make_float2(fa.z, fa.w));
        __hip_bfloat162 h2 = __float22bfloat162_rn(make_float2(fb.x, fb.y));
        __hip_bfloat162 h3 = __float22bfloat162_rn(make_float2(fb.z, fb.w));
        ua.u[0] = *(uint*)&h0; ua.u[1] = *(uint*)&h1;
        ua.u[2] = *(uint*)&h2; ua.u[3] = *(uint*)&h3;
#pragma unroll
        for (int nt = 0; nt < 8; ++nt) {
            int n = nt * 16 + l16;
            short8 b = *(const short8*)((const short*)wT + (size_t)n * 640 + 512 + k0);
            acc[nt] = __builtin_amdgcn_mfma_f32_16x16x32_bf16(ua.s, b, acc[nt], 0, 0, 0);
        }
    }

    // relu(+bias) -> LDS tile (C-layout write, unguarded: tile is block-local)
#pragma unroll
    for (int nt = 0; nt < 8; ++nt) {
        float bs = bias[nt * 16 + l16];
#pragma unroll
        for (int i = 0; i < 4; ++i) {
            float v = fmaxf(acc[nt][i] + bs, 0.f);
            __hip_bfloat16 h = __float2bfloat16(v);
            tl[quad * 4 + i][nt * 16 + l16] = *(short*)&h;
        }
    }
    __syncthreads();

    // ---- NGNN layers: K=128 each, A from LDS tile ----
#pragma unroll
    for (int l = 0; l < 2; ++l) {
        const unsigned short* wl = wT2 + l * 16384;
        short8 af[4];
#pragma unroll
        for (int ks = 0; ks < 4; ++ks)
            af[ks] = *(const short8*)&tl[l16][ks * 32 + koff];
        floatx4 acc2[8];
#pragma unroll
        for (int nt = 0; nt < 8; ++nt) acc2[nt] = (floatx4){0.f, 0.f, 0.f, 0.f};
#pragma unroll
        for (int ks = 0; ks < 4; ++ks) {
            int k0 = ks * 32 + koff;
#pragma unroll
            for (int nt = 0; nt < 8; ++nt) {
                int n = nt * 16 + l16;
                short8 b = *(const short8*)((const short*)wl + (size_t)n * 128 + k0);
                acc2[nt] = __builtin_amdgcn_mfma_f32_16x16x32_bf16(af[ks], b, acc2[nt], 0, 0, 0);
            }
        }
        if (l == 0) {
            __syncthreads();   // all af reads done before overwrite
#pragma unroll
            for (int nt = 0; nt < 8; ++nt)
#pragma unroll
                for (int i = 0; i < 4; ++i) {
                    float v = fmaxf(acc2[nt][i], 0.f);
                    __hip_bfloat16 h = __float2bfloat16(v);
                    tl[quad * 4 + i][nt * 16 + l16] = *(short*)&h;
                }
            __syncthreads();
        } else {
#pragma unroll
            for (int nt = 0; nt < 8; ++nt) {
                int n = nt * 16 + l16;
#pragma unroll
                for (int i = 0; i < 4; ++i) {
                    int m = row0 + quad * 4 + i;
                    if (m < N_NODES)
                        out[(size_t)m * D_FEAT + n] = fmaxf(acc2[nt][i], 0.f);
                }
            }
        }
    }
}

extern "C" void kernel_launch(void* const* d_in, const int* in_sizes, int n_in,
                              void* d_out, int out_size, void* d_ws, size_t ws_size,
                              hipStream_t stream) {
    const float* x           = (const float*)d_in[0];
    const int*   edge_src    = (const int*)d_in[1];
    const int*   edge_dst    = (const int*)d_in[2];
    const float* w_comp      = (const float*)d_in[3];
    const float* bases       = (const float*)d_in[4];
    const float* loop_weight = (const float*)d_in[5];
    const float* h_bias      = (const float*)d_in[6];
    const float* ngnn_w      = (const float*)d_in[7];
    float* out = (float*)d_out;

    // workspace layout (~131.6 MB base; +25.6 MB optional xb)
    char* ws = (char*)d_ws;
    size_t off = 0;
    __hip_bfloat162* y = (__hip_bfloat162*)(ws + off);
    off += (size_t)N_NODES * 512 * 2;              // 102.4 MB
    int* ebuf2 = (int*)(ws + off);                 // 784*9216*4 = 28.9 MB
    off += (size_t)NBKT * BKT_CAP * 4;
    int* gcursor = (int*)(ws + off);
    off += 4096;
    unsigned short* wT = (unsigned short*)(ws + off);
    off += (size_t)128 * 640 * 2;                  // 160 KB
    unsigned short* wT2 = (unsigned short*)(ws + off);
    off += (size_t)2 * 128 * 128 * 2;              // 64 KB
    uint* xb = (uint*)(ws + off);
    size_t xb_bytes = (size_t)N_NODES * 64 * 4;    // 25.6 MB
    const bool use_bf16_x = (ws_size >= off + xb_bytes);   // ws_size constant across calls

    const int GEMM_GRID = (N_NODES + 63) / 64;     // 1563

    // 0) weight/x conversions
    wcvt_kernel<<<(128 * 640 + 255) / 256, 256, 0, stream>>>(bases, loop_weight, wT);
    wcvt2_kernel<<<(2 * 128 * 128 + 255) / 256, 256, 0, stream>>>(ngnn_w, wT2);
    if (use_bf16_x)
        xcvt_kernel<<<(N_NODES * 64 + 255) / 256, 256, 0, stream>>>(x, xb);

    // 1) bucket partition
    init_cursor_kernel<<<1, 1024, 0, stream>>>(gcursor);
    p1_kernel<<<P1_NWG, P1_TPB, 0, stream>>>(edge_src, edge_dst, gcursor, ebuf2);

    // 2) fused filter + LDS-sort + gather -> y (bf16, basis-combined, deg-normalized)
    if (use_bf16_x)
        agg3_kernel<true><<<SGRID, 512, 0, stream>>>(x, xb, gcursor, ebuf2, w_comp, y);
    else
        agg3_kernel<false><<<SGRID, 512, 0, stream>>>(x, nullptr, gcursor, ebuf2, w_comp, y);

    // 3) fused MLP: gemm_big + ngnn0 + ngnn1 in one pass (row-local chain)
    fused_mlp<<<GEMM_GRID, 256, 0, stream>>>(
        (const short*)y, x, wT, h_bias, wT2, out);
}

// Round 7
// 597.320 us; speedup vs baseline: 2.8594x; 1.1307x over previous
//
#include <hip/hip_runtime.h>
#include <hip/hip_bf16.h>

#define N_NODES 100000
#define R_REL   8
#define E_EDGES 800000
#define D_FEAT  128
#define B_BASES 4
#define RN      (R_REL * N_NODES)
#define RE      (R_REL * E_EDGES)          // 6.4M edges

// radix partition: 784 coarse buckets of 128 dst nodes each
#define NBKT    784
#define BKT_CAP 9216                       // mean 8163, +11 sigma slack
#define P1_TPB  256
#define P1_EPT  32
#define P1_CHUNK (P1_TPB * P1_EPT)         // 8192 edges / WG
#define P1_NWG  ((RE + P1_CHUNK - 1) / P1_CHUNK)   // 782

// agg: 4 sub-buckets of 32 dst nodes per coarse bucket
#define SUB_PER_BKT 4
#define SGRID   (NBKT * SUB_PER_BKT)       // 3136
#define SUBCAP  2816                       // mean 2041, +17 sigma slack

#define NXW  (N_NODES * 64)                // xcvt items
#define NW1  (128 * 640)                   // wcvt items
#define NW2  (2 * 128 * 128)               // wcvt2 items

typedef __attribute__((ext_vector_type(8))) short short8;
typedef __attribute__((ext_vector_type(4))) float floatx4;

// ---- fused prep: xcvt + wcvt + wcvt2 + cursor init in ONE launch ----------
__global__ __launch_bounds__(256) void prep_kernel(
    const float* __restrict__ x, uint* __restrict__ xb,
    const float* __restrict__ bases, const float* __restrict__ loopw,
    unsigned short* __restrict__ wT,
    const float* __restrict__ ngnn_w, unsigned short* __restrict__ wT2,
    int* __restrict__ gcursor, int do_x) {
    int idx = blockIdx.x * 256 + threadIdx.x;
    if (do_x) {
        if (idx < NXW) {                       // x (fp32) -> xb (bf162 pairs)
            float2 v = *(const float2*)(x + 2 * (size_t)idx);
            __hip_bfloat162 h = __float22bfloat162_rn(v);
            xb[idx] = *(uint*)&h;
            return;
        }
        idx -= NXW;
    }
    if (idx < NW1) {                           // wT[n][k]
        int n = idx / 640, k = idx % 640;
        float v = (k < 512) ? bases[(size_t)k * 128 + n]
                            : loopw[(size_t)(k - 512) * 128 + n];
        __hip_bfloat16 h = __float2bfloat16(v);
        wT[idx] = *(unsigned short*)&h;
        return;
    }
    idx -= NW1;
    if (idx < NW2) {                           // wT2[l][n][k]
        int l = idx >> 14, rem = idx & 16383;
        int n = rem >> 7, k = rem & 127;
        float v = ngnn_w[(size_t)l * 16384 + (size_t)k * 128 + n];
        __hip_bfloat16 h = __float2bfloat16(v);
        wT2[idx] = *(unsigned short*)&h;
        return;
    }
    idx -= NW2;
    if (idx < NBKT) gcursor[idx] = idx * BKT_CAP;
}

// ---- pass 1: partition edges into coarse dst-buckets (coalesced writes) ---
// record = src(17b) | dst_low(7b)<<17 | r(3b)<<24
__global__ __launch_bounds__(256) void p1_kernel(
    const int* __restrict__ src, const int* __restrict__ dst,
    int* __restrict__ gcursor, int* __restrict__ ebuf2) {
    __shared__ int hist[NBKT];
    __shared__ int cnt2[NBKT];
    __shared__ int basebkt[NBKT];
    __shared__ int lofs[NBKT];
    __shared__ int aux[256];
    __shared__ int recs[P1_CHUNK];           // 32 KB
    __shared__ unsigned short bb[P1_CHUNK];  // 16 KB
    int t = threadIdx.x;
    for (int i = t; i < NBKT; i += 256) { hist[i] = 0; cnt2[i] = 0; }
    __syncthreads();

    int e0 = blockIdx.x * P1_CHUNK;
    int rec[P1_EPT];
    int bkt[P1_EPT];
#pragma unroll
    for (int i = 0; i < P1_EPT; ++i) {
        int e = e0 + i * P1_TPB + t;         // coalesced
        if (e < RE) {
            int d = dst[e];
            int s = src[e];
            int r = e / E_EDGES;             // magic-mul division
            bkt[i] = d >> 7;
            rec[i] = s | ((d & 127) << 17) | (r << 24);
            atomicAdd(&hist[bkt[i]], 1);     // native int ds_add
        } else bkt[i] = -1;
    }
    __syncthreads();

    // exclusive scan of hist[784]: 4 consecutive per thread + Hillis-Steele
    int k0 = t * 4;
    int c0 = (k0 + 0 < NBKT) ? hist[k0 + 0] : 0;
    int c1 = (k0 + 1 < NBKT) ? hist[k0 + 1] : 0;
    int c2 = (k0 + 2 < NBKT) ? hist[k0 + 2] : 0;
    int c3 = (k0 + 3 < NBKT) ? hist[k0 + 3] : 0;
    int s1 = c0 + c1, s2 = s1 + c2, s3 = s2 + c3;
    aux[t] = s3;
    __syncthreads();
    int vv = s3;
    for (int off = 1; off < 256; off <<= 1) {
        int yv = (t >= off) ? aux[t - off] : 0;
        __syncthreads();
        vv += yv;
        aux[t] = vv;
        __syncthreads();
    }
    int total = aux[255];
    int texcl = vv - s3;
    if (k0 + 0 < NBKT) lofs[k0 + 0] = texcl;
    if (k0 + 1 < NBKT) lofs[k0 + 1] = texcl + c0;
    if (k0 + 2 < NBKT) lofs[k0 + 2] = texcl + s1;
    if (k0 + 3 < NBKT) lofs[k0 + 3] = texcl + s2;
    __syncthreads();
    for (int i = t; i < NBKT; i += 256) {
        int hv = hist[i];
        basebkt[i] = (hv > 0) ? atomicAdd(&gcursor[i], hv) : 0;
    }
    __syncthreads();

    // reorder records into bucket-contiguous LDS slots
#pragma unroll
    for (int i = 0; i < P1_EPT; ++i) {
        if (bkt[i] >= 0) {
            int p = lofs[bkt[i]] + atomicAdd(&cnt2[bkt[i]], 1);
            recs[p] = rec[i];
            bb[p] = (unsigned short)bkt[i];
        }
    }
    __syncthreads();

    // writeout: consecutive i are mostly same-bucket runs
    for (int i = t; i < total; i += 256) {
        int b = bb[i];
        int p2 = basebkt[b] + (i - lofs[b]);
        if (p2 < (b + 1) * BKT_CAP) ebuf2[p2] = recs[i];
    }
}

// ---- fused sort+gather (R1 structure, proven 269 us) ---------------------
// 512 thr (8 waves), 4 WGs/CU (~25 KB LDS). id = sub*784 + bucket: the 4
// sub-WGs of one bucket are congruent mod 8 (784 % 8 == 0) -> same XCD
// under round-robin dispatch, so the 4x coarse-bucket re-read hits one L2.
template <bool XB>
__global__ __launch_bounds__(512, 8) void agg3_kernel(
    const float* __restrict__ x,
    const uint*  __restrict__ xb,          // [N][64] bf162 pairs
    const int*   __restrict__ gcursor,
    const int*   __restrict__ ebuf2,
    const float* __restrict__ w_comp,
    __hip_bfloat162* __restrict__ y) {     // [N][256] bf162
    __shared__ int raw[SUBCAP];            // 11 KB
    __shared__ int sorted[SUBCAP];         // 11 KB (head doubles as scan aux)
    __shared__ int cursors[256];
    __shared__ int segbeg[256];
    __shared__ int nraw;
    const int t = threadIdx.x;
    const int bucket = blockIdx.x % NBKT;  // co-XCD mapping for the 4 sub-WGs
    const int sub    = blockIdx.x / NBKT;

    int cnt = gcursor[bucket] - bucket * BKT_CAP;
    if (cnt > BKT_CAP) cnt = BKT_CAP;
    const int* brec = ebuf2 + (size_t)bucket * BKT_CAP;
    if (t < 256) cursors[t] = 0;
    if (t == 0) nraw = 0;
    __syncthreads();

    const int lane = t & 63;
    const unsigned long long lmask = (1ull << lane) - 1ull;

    // single global pass: compact matching records into raw[] + histogram
    for (int i0 = 0; i0 < cnt; i0 += 512) {
        int i = i0 + t;
        int rec = (i < cnt) ? brec[i] : 0;
        bool match = (i < cnt) && ((((rec >> 17) & 127) >> 5) == sub);
        unsigned long long mask = __ballot(match);
        int base = 0;
        if (lane == 0) base = atomicAdd(&nraw, (int)__popcll(mask));
        base = __shfl(base, 0);
        if (match) {
            int p = base + (int)__popcll(mask & lmask);
            if (p < SUBCAP) {
                raw[p] = rec;
                int key = ((rec >> 17) & 31) * 8 + ((rec >> 24) & 7);
                atomicAdd(&cursors[key], 1);
            }
        }
    }
    __syncthreads();
    int n = nraw; if (n > SUBCAP) n = SUBCAP;

    // exclusive scan of 256 degrees (aux aliases sorted[0..511])
    int deg = (t < 256) ? cursors[t] : 0;
    int* aux = sorted;
    aux[t] = deg;
    __syncthreads();
    int vv = deg;
    for (int off = 1; off < 256; off <<= 1) {
        int yv = (t >= off && t < 256) ? aux[t - off] : 0;
        __syncthreads();
        vv += yv;
        aux[t] = vv;
        __syncthreads();
    }
    if (t < 256) {
        cursors[t] = vv - deg;
        segbeg[t]  = vv - deg;
    }
    __syncthreads();

    // in-LDS scatter to sorted order (src ids only)
    for (int i = t; i < n; i += 512) {
        int rec = raw[i];
        int key = ((rec >> 17) & 31) * 8 + ((rec >> 24) & 7);
        int pos = atomicAdd(&cursors[key], 1);   // ds_add_rtn_u32
        sorted[pos] = rec & 0x1FFFF;
    }
    __syncthreads();

    // gather: wave owns 4 nodes; per (node,r) segment sum then basis fold
    const int wid = t >> 6;
    const float* xp  = x + 2 * lane;
    const uint*  xbp = xb + lane;
    for (int nn = 0; nn < 4; ++nn) {
        int nl = wid * 4 + nn;                   // 0..31 within sub-bucket
        int node = bucket * 128 + sub * 32 + nl;
        int key0 = nl * 8;
        float2 acc[B_BASES];
#pragma unroll
        for (int b = 0; b < B_BASES; ++b) acc[b] = make_float2(0.f, 0.f);
#pragma unroll
        for (int r = 0; r < R_REL; ++r) {
            int b0 = segbeg[key0 + r];
            int e0 = cursors[key0 + r];      // post-scatter == segment end
            int d = e0 - b0;
            float inv = 1.0f / (float)(d > 1 ? d : 1);
            float ax = 0.f, ay = 0.f;
            int i = b0;
            for (; i + 3 < e0; i += 4) {
                int s0 = sorted[i], s1 = sorted[i + 1], s2 = sorted[i + 2], s3 = sorted[i + 3];
                if (XB) {
                    uint u0 = xbp[(size_t)s0 * 64];
                    uint u1 = xbp[(size_t)s1 * 64];
                    uint u2 = xbp[(size_t)s2 * 64];
                    uint u3 = xbp[(size_t)s3 * 64];
                    ax += (__uint_as_float(u0 << 16) + __uint_as_float(u1 << 16))
                        + (__uint_as_float(u2 << 16) + __uint_as_float(u3 << 16));
                    ay += (__uint_as_float(u0 & 0xFFFF0000u) + __uint_as_float(u1 & 0xFFFF0000u))
                        + (__uint_as_float(u2 & 0xFFFF0000u) + __uint_as_float(u3 & 0xFFFF0000u));
                } else {
                    float2 a = *(const float2*)(xp + (size_t)s0 * D_FEAT);
                    float2 b = *(const float2*)(xp + (size_t)s1 * D_FEAT);
                    float2 cc = *(const float2*)(xp + (size_t)s2 * D_FEAT);
                    float2 d2 = *(const float2*)(xp + (size_t)s3 * D_FEAT);
                    ax += (a.x + b.x) + (cc.x + d2.x);
                    ay += (a.y + b.y) + (cc.y + d2.y);
                }
            }
            for (; i < e0; ++i) {
                int s = sorted[i];
                if (XB) {
                    uint u = xbp[(size_t)s * 64];
                    ax += __uint_as_float(u << 16);
                    ay += __uint_as_float(u & 0xFFFF0000u);
                } else {
                    float2 a = *(const float2*)(xp + (size_t)s * D_FEAT);
                    ax += a.x; ay += a.y;
                }
            }
#pragma unroll
            for (int b = 0; b < B_BASES; ++b) {
                float coef = w_comp[r * B_BASES + b] * inv;
                acc[b].x = fmaf(coef, ax, acc[b].x);
                acc[b].y = fmaf(coef, ay, acc[b].y);
            }
        }
        if (node < N_NODES) {
#pragma unroll
            for (int b = 0; b < B_BASES; ++b)
                y[(size_t)node * 256 + b * 64 + lane] = __float22bfloat162_rn(acc[b]);
        }
    }
}

// ---- fused MLP v2: M=32 rows/wave (each B-load feeds 2 MFMAs) ------------
// out = relu(relu(relu([y|x]@wT^T + bias) @ w0) @ w1). Block = 4 waves x 32
// rows = 128 rows. Intermediate activations in per-wave padded LDS tile
// (32 x 136 bf16) converting C-fragment layout -> A-fragment layout.
// Self-loop K-range reads xb (bf16) directly when available.
#define TPAD 136
template <bool XB>
__global__ __launch_bounds__(256) void fused_mlp(
    const short* __restrict__ y,            // [N][512] bf16
    const float* __restrict__ x,            // [N][128] fp32
    const uint*  __restrict__ xb,           // [N][64] bf162 pairs
    const unsigned short* __restrict__ wT,  // [128][640] bf16, n-major
    const float* __restrict__ bias,
    const unsigned short* __restrict__ wT2, // [2][128][128] bf16, n-major
    float* __restrict__ out) {              // [N][128] fp32
    __shared__ short tile[4][32][TPAD];     // 34.8 KB
    const int wave = threadIdx.x >> 6;
    const int lane = threadIdx.x & 63;
    const int quad = lane >> 4;
    const int l16  = lane & 15;
    const int rbase = blockIdx.x * 128 + wave * 32;
    int r0 = rbase + l16;      if (r0 >= N_NODES) r0 = N_NODES - 1;
    int r1 = rbase + 16 + l16; if (r1 >= N_NODES) r1 = N_NODES - 1;
    short (*tl)[TPAD] = tile[wave];
    const int koff = quad * 8;

    floatx4 acc0[8], acc1[8];
#pragma unroll
    for (int nt = 0; nt < 8; ++nt) {
        acc0[nt] = (floatx4){0.f, 0.f, 0.f, 0.f};
        acc1[nt] = (floatx4){0.f, 0.f, 0.f, 0.f};
    }

    // ---- layer 0: [y | x] @ wT^T, K=640; one B-load feeds both row-groups
    const short* y0 = y + (size_t)r0 * 512;
    const short* y1 = y + (size_t)r1 * 512;
    for (int ks = 0; ks < 16; ++ks) {
        int k0 = ks * 32 + koff;
        short8 a0 = *(const short8*)(y0 + k0);
        short8 a1 = *(const short8*)(y1 + k0);
#pragma unroll
        for (int nt = 0; nt < 8; ++nt) {
            int n = nt * 16 + l16;
            short8 b = *(const short8*)((const short*)wT + (size_t)n * 640 + k0);
            acc0[nt] = __builtin_amdgcn_mfma_f32_16x16x32_bf16(a0, b, acc0[nt], 0, 0, 0);
            acc1[nt] = __builtin_amdgcn_mfma_f32_16x16x32_bf16(a1, b, acc1[nt], 0, 0, 0);
        }
    }
    if (XB) {
        const short* xb0 = (const short*)xb + (size_t)r0 * 128;
        const short* xb1 = (const short*)xb + (size_t)r1 * 128;
#pragma unroll
        for (int ks = 0; ks < 4; ++ks) {
            int kl = ks * 32 + koff;
            short8 a0 = *(const short8*)(xb0 + kl);
            short8 a1 = *(const short8*)(xb1 + kl);
#pragma unroll
            for (int nt = 0; nt < 8; ++nt) {
                int n = nt * 16 + l16;
                short8 b = *(const short8*)((const short*)wT + (size_t)n * 640 + 512 + kl);
                acc0[nt] = __builtin_amdgcn_mfma_f32_16x16x32_bf16(a0, b, acc0[nt], 0, 0, 0);
                acc1[nt] = __builtin_amdgcn_mfma_f32_16x16x32_bf16(a1, b, acc1[nt], 0, 0, 0);
            }
        }
    } else {
        const float* x0 = x + (size_t)r0 * 128;
        const float* x1 = x + (size_t)r1 * 128;
#pragma unroll
        for (int ks = 0; ks < 4; ++ks) {
            int kl = ks * 32 + koff;
            union { short8 s; uint u[4]; } ua0, ua1;
            {
                float4 fa = *(const float4*)(x0 + kl);
                float4 fb = *(const float4*)(x0 + kl + 4);
                __hip_bfloat162 h0 = __float22bfloat162_rn(make_float2(fa.x, fa.y));
                __hip_bfloat162 h1 = __float22bfloat162_rn(make_float2(fa.z, fa.w));
                __hip_bfloat162 h2 = __float22bfloat162_rn(make_float2(fb.x, fb.y));
                __hip_bfloat162 h3 = __float22bfloat162_rn(make_float2(fb.z, fb.w));
                ua0.u[0] = *(uint*)&h0; ua0.u[1] = *(uint*)&h1;
                ua0.u[2] = *(uint*)&h2; ua0.u[3] = *(uint*)&h3;
            }
            {
                float4 fa = *(const float4*)(x1 + kl);
                float4 fb = *(const float4*)(x1 + kl + 4);
                __hip_bfloat162 h0 = __float22bfloat162_rn(make_float2(fa.x, fa.y));
                __hip_bfloat162 h1 = __float22bfloat162_rn(make_float2(fa.z, fa.w));
                __hip_bfloat162 h2 = __float22bfloat162_rn(make_float2(fb.x, fb.y));
                __hip_bfloat162 h3 = __float22bfloat162_rn(make_float2(fb.z, fb.w));
                ua1.u[0] = *(uint*)&h0; ua1.u[1] = *(uint*)&h1;
                ua1.u[2] = *(uint*)&h2; ua1.u[3] = *(uint*)&h3;
            }
#pragma unroll
            for (int nt = 0; nt < 8; ++nt) {
                int n = nt * 16 + l16;
                short8 b = *(const short8*)((const short*)wT + (size_t)n * 640 + 512 + kl);
                acc0[nt] = __builtin_amdgcn_mfma_f32_16x16x32_bf16(ua0.s, b, acc0[nt], 0, 0, 0);
                acc1[nt] = __builtin_amdgcn_mfma_f32_16x16x32_bf16(ua1.s, b, acc1[nt], 0, 0, 0);
            }
        }
    }

    // relu(+bias) -> LDS tile (C-layout write; tile is wave-local)
#pragma unroll
    for (int nt = 0; nt < 8; ++nt) {
        float bs = bias[nt * 16 + l16];
#pragma unroll
        for (int i = 0; i < 4; ++i) {
            int row = quad * 4 + i;
            float v0 = fmaxf(acc0[nt][i] + bs, 0.f);
            float v1 = fmaxf(acc1[nt][i] + bs, 0.f);
            __hip_bfloat16 h0 = __float2bfloat16(v0);
            __hip_bfloat16 h1 = __float2bfloat16(v1);
            tl[row][nt * 16 + l16]      = *(short*)&h0;
            tl[16 + row][nt * 16 + l16] = *(short*)&h1;
        }
    }
    __syncthreads();

    // ---- NGNN layers: K=128 each, A from LDS tile ----
#pragma unroll
    for (int l = 0; l < 2; ++l) {
        const unsigned short* wl = wT2 + l * 16384;
        short8 af0[4], af1[4];
#pragma unroll
        for (int ks = 0; ks < 4; ++ks) {
            af0[ks] = *(const short8*)&tl[l16][ks * 32 + koff];
            af1[ks] = *(const short8*)&tl[16 + l16][ks * 32 + koff];
        }
        floatx4 ac0[8], ac1[8];
#pragma unroll
        for (int nt = 0; nt < 8; ++nt) {
            ac0[nt] = (floatx4){0.f, 0.f, 0.f, 0.f};
            ac1[nt] = (floatx4){0.f, 0.f, 0.f, 0.f};
        }
#pragma unroll
        for (int ks = 0; ks < 4; ++ks) {
            int k0 = ks * 32 + koff;
#pragma unroll
            for (int nt = 0; nt < 8; ++nt) {
                int n = nt * 16 + l16;
                short8 b = *(const short8*)((const short*)wl + (size_t)n * 128 + k0);
                ac0[nt] = __builtin_amdgcn_mfma_f32_16x16x32_bf16(af0[ks], b, ac0[nt], 0, 0, 0);
                ac1[nt] = __builtin_amdgcn_mfma_f32_16x16x32_bf16(af1[ks], b, ac1[nt], 0, 0, 0);
            }
        }
        if (l == 0) {
            __syncthreads();   // all af reads done before overwrite
#pragma unroll
            for (int nt = 0; nt < 8; ++nt)
#pragma unroll
                for (int i = 0; i < 4; ++i) {
                    int row = quad * 4 + i;
                    float v0 = fmaxf(ac0[nt][i], 0.f);
                    float v1 = fmaxf(ac1[nt][i], 0.f);
                    __hip_bfloat16 h0 = __float2bfloat16(v0);
                    __hip_bfloat16 h1 = __float2bfloat16(v1);
                    tl[row][nt * 16 + l16]      = *(short*)&h0;
                    tl[16 + row][nt * 16 + l16] = *(short*)&h1;
                }
            __syncthreads();
        } else {
#pragma unroll
            for (int nt = 0; nt < 8; ++nt) {
                int n = nt * 16 + l16;
#pragma unroll
                for (int i = 0; i < 4; ++i) {
                    int m0 = rbase + quad * 4 + i;
                    int m1 = rbase + 16 + quad * 4 + i;
                    if (m0 < N_NODES)
                        out[(size_t)m0 * D_FEAT + n] = fmaxf(ac0[nt][i], 0.f);
                    if (m1 < N_NODES)
                        out[(size_t)m1 * D_FEAT + n] = fmaxf(ac1[nt][i], 0.f);
                }
            }
        }
    }
}

extern "C" void kernel_launch(void* const* d_in, const int* in_sizes, int n_in,
                              void* d_out, int out_size, void* d_ws, size_t ws_size,
                              hipStream_t stream) {
    const float* x           = (const float*)d_in[0];
    const int*   edge_src    = (const int*)d_in[1];
    const int*   edge_dst    = (const int*)d_in[2];
    const float* w_comp      = (const float*)d_in[3];
    const float* bases       = (const float*)d_in[4];
    const float* loop_weight = (const float*)d_in[5];
    const float* h_bias      = (const float*)d_in[6];
    const float* ngnn_w      = (const float*)d_in[7];
    float* out = (float*)d_out;

    // workspace layout (~131.6 MB base; +25.6 MB optional xb)
    char* ws = (char*)d_ws;
    size_t off = 0;
    __hip_bfloat162* y = (__hip_bfloat162*)(ws + off);
    off += (size_t)N_NODES * 512 * 2;              // 102.4 MB
    int* ebuf2 = (int*)(ws + off);                 // 784*9216*4 = 28.9 MB
    off += (size_t)NBKT * BKT_CAP * 4;
    int* gcursor = (int*)(ws + off);
    off += 4096;
    unsigned short* wT = (unsigned short*)(ws + off);
    off += (size_t)128 * 640 * 2;                  // 160 KB
    unsigned short* wT2 = (unsigned short*)(ws + off);
    off += (size_t)2 * 128 * 128 * 2;              // 64 KB
    uint* xb = (uint*)(ws + off);
    size_t xb_bytes = (size_t)N_NODES * 64 * 4;    // 25.6 MB
    const bool use_bf16_x = (ws_size >= off + xb_bytes);   // ws_size constant across calls

    // 0) fused prep: xcvt + wcvt + wcvt2 + cursor init (one launch)
    int prep_items = (use_bf16_x ? NXW : 0) + NW1 + NW2 + NBKT;
    prep_kernel<<<(prep_items + 255) / 256, 256, 0, stream>>>(
        x, xb, bases, loop_weight, wT, ngnn_w, wT2, gcursor, use_bf16_x ? 1 : 0);

    // 1) bucket partition
    p1_kernel<<<P1_NWG, P1_TPB, 0, stream>>>(edge_src, edge_dst, gcursor, ebuf2);

    // 2) fused filter + LDS-sort + gather -> y (bf16, basis-combined, deg-normalized)
    if (use_bf16_x)
        agg3_kernel<true><<<SGRID, 512, 0, stream>>>(x, xb, gcursor, ebuf2, w_comp, y);
    else
        agg3_kernel<false><<<SGRID, 512, 0, stream>>>(x, nullptr, gcursor, ebuf2, w_comp, y);

    // 3) fused MLP: gemm_big + ngnn0 + ngnn1, M=32 rows/wave
    const int MLP_GRID = (N_NODES + 127) / 128;    // 782
    if (use_bf16_x)
        fused_mlp<true><<<MLP_GRID, 256, 0, stream>>>(
            (const short*)y, x, xb, wT, h_bias, wT2, out);
    else
        fused_mlp<false><<<MLP_GRID, 256, 0, stream>>>(
            (const short*)y, x, nullptr, wT, h_bias, wT2, out);
}